// Round 4
// baseline (1304.783 us; speedup 1.0000x reference)
//
#include <hip/hip_runtime.h>
#include <hip/hip_bf16.h>

#define N_NODES 50000
#define N_EDGES 600000
#define TOT_E   (N_EDGES + N_NODES)   // 650000 with self loops
#define NLAYER  3

typedef __hip_bfloat16 bf16;
__device__ __forceinline__ float b2f(bf16 v){ return __bfloat162float(v); }

// ---- ordered-uint encoding for float atomicMax ----
__device__ __forceinline__ unsigned fenc(float f){
  unsigned u = __float_as_uint(f);
  return (u & 0x80000000u) ? ~u : (u | 0x80000000u);
}
__device__ __forceinline__ float fdec(unsigned u){
  unsigned v = (u & 0x80000000u) ? (u & 0x7fffffffu) : ~u;
  return __uint_as_float(v);
}

// dual-mode load: m=1 -> f32, m=0 -> bf16
__device__ __forceinline__ float ldm(const void* p, long i, int m){
  return m ? ((const float*)p)[i] : b2f(((const bf16*)p)[i]);
}

// ================= input dtype detection =================
// Probe enc_w (1920 elems, true values ~N(0,0.05^2)). If buffer is f32,
// bf16-reading yields garbage exponents (values >>1000). mode=1 -> f32.
__global__ void detect_kernel(const void* probe, int* mode){
  __shared__ float red[256];
  int t = threadIdx.x;
  const bf16* p = (const bf16*)probe;
  float mx = 0.f;
  for (int i = t; i < 1920; i += 256){
    float v = fabsf(b2f(p[i]));
    if (!isfinite(v)) v = 1e30f;
    mx = fmaxf(mx, v);
  }
  red[t] = mx; __syncthreads();
  if (t == 0){
    float m = 0.f;
    for (int i = 0; i < 256; i++) m = fmaxf(m, red[i]);
    mode[0] = (m > 1000.0f) ? 1 : 0;
  }
}

// ================= edge_index sanity =================
__global__ void check_ei_kernel(const int* __restrict__ ei, int* devflags){
  int t = blockIdx.x*256 + threadIdx.x;
  if (t < 2*N_EDGES){
    int v = ei[t];
    if (v < 0 || v >= N_NODES) atomicOr(&devflags[0], 1);
  }
  if (t < 1024){
    if (ei[2*t + 1] == 0) atomicAdd(&devflags[1], 1);
  }
}

// ================= sentinel (f32 output) =================
__global__ void sentinel_kernel(int host_code, const int* devflags, const int* mode, float* out){
  if (threadIdx.x == 0 && blockIdx.x == 0){
    int code = host_code;
    if (!code && devflags){
      if (devflags[1] > 900)      code = 16384;  // edge_index looks int64
      else if (devflags[0])       code = 20480;  // edge_index out of bounds
    }
    if (code){
      if (mode) code += 512*mode[0];
      out[0] = (float)code;
    }
  }
}

// ================= small weight conversion =================
struct CvtTab { const void* s[27]; float* d[27]; int n[27]; };
__global__ void cvt_small_kernel(CvtTab tab, const int* mode){
  int b = blockIdx.x;
  int m = mode[0];
  const void* s = tab.s[b]; float* d = tab.d[b]; int n = tab.n[b];
  for (int i = threadIdx.x; i < n; i += 256) d[i] = ldm(s, i, m);
}

// ================= CSR build =================
__global__ void count_kernel(const int* __restrict__ ei, const void* __restrict__ ea_raw,
                             const int* __restrict__ mode, int* __restrict__ cnt,
                             float* __restrict__ ea_sum){
  int e = blockIdx.x*256 + threadIdx.x;
  if (e >= N_EDGES) return;
  int m = mode[0];
  int d = ei[N_EDGES + e];
  atomicAdd(&cnt[d], 1);
  #pragma unroll
  for (int k = 0; k < 10; k++) atomicAdd(&ea_sum[d*10+k], ldm(ea_raw, (long)e*10+k, m));
}

__global__ __launch_bounds__(1024) void rowptr_kernel(const int* __restrict__ cnt, int* __restrict__ rowptr){
  __shared__ int part[1024];
  int t = threadIdx.x;
  const int CH = (N_NODES + 1023)/1024;        // 49
  int b = t*CH, e = min(b+CH, N_NODES);
  int loc = 0;
  for (int i = b; i < e; i++) loc += cnt[i] + 1;   // +1 self loop
  part[t] = loc;
  __syncthreads();
  if (t == 0){
    int run = 0;
    for (int i = 0; i < 1024; i++){ int tmp = part[i]; part[i] = run; run += tmp; }
    rowptr[N_NODES] = run;
  }
  __syncthreads();
  int run = part[t];
  for (int i = b; i < e; i++){ rowptr[i] = run; run += cnt[i] + 1; }
}

__global__ void selfdiv_kernel(const int* __restrict__ cnt, float* __restrict__ ea_sum){
  int t = blockIdx.x*256 + threadIdx.x;
  if (t >= N_NODES*10) return;
  int i = t / 10;
  ea_sum[t] /= fmaxf((float)cnt[i], 1.0f);
}

__global__ void scatter_kernel(const int* __restrict__ ei, const int* __restrict__ rowptr,
                               int* __restrict__ fill, int* __restrict__ srcs, int* __restrict__ eid){
  int e = blockIdx.x*256 + threadIdx.x;
  if (e >= TOT_E) return;
  if (e < N_EDGES){
    int s = ei[e], d = ei[N_EDGES + e];
    int pos = rowptr[d] + atomicAdd(&fill[d], 1);
    srcs[pos] = s; eid[pos] = e;
  } else {
    int i = e - N_EDGES;
    int pos = rowptr[i+1] - 1;                 // reserved last slot = self loop
    srcs[pos] = i; eid[pos] = e;
  }
}

// ================= weight packing =================
__global__ void pack_kernel(const float* __restrict__ head_w1, const float* __restrict__ strat_w1,
                            const float* __restrict__ head_b1, const float* __restrict__ strat_b1,
                            float* __restrict__ W1cat, float* __restrict__ b1cat){
  int t = blockIdx.x*256 + threadIdx.x;
  if (t < 128*160){
    int f = t / 160, c = t % 160;
    W1cat[t] = (c < 128) ? head_w1[(c>>5)*4096 + f*32 + (c&31)]
                         : strat_w1[f*32 + (c-128)];
  }
  if (t < 160) b1cat[t] = (t < 128) ? head_b1[t] : strat_b1[t-128];
}

// M[l][k][h] = sum_d We[l][k][h*32+d] * att_edge[l][h][d]
__global__ void mmat_kernel(const float* __restrict__ We, const float* __restrict__ att_edge,
                            float* __restrict__ M){
  int t = threadIdx.x;
  if (t >= 120) return;
  int l = t / 40, r = t % 40, k = r / 4, hh = r % 4;
  float s = 0;
  #pragma unroll
  for (int d = 0; d < 32; d++)
    s += We[l*1280 + k*128 + hh*32 + d] * att_edge[l*128 + hh*32 + d];
  M[t] = s;
}

// ================= encoder (dual-mode x) =================
__global__ __launch_bounds__(128) void encoder_kernel(const void* __restrict__ x_raw, const int* __restrict__ mode,
                                                      const float* __restrict__ enc_w, const float* __restrict__ enc_b,
                                                      float* __restrict__ h){
  __shared__ float xs[16];
  int n = blockIdx.x, j = threadIdx.x;
  if (j < 15) xs[j] = ldm(x_raw, (long)n*15 + j, mode[0]);
  __syncthreads();
  float acc = enc_b[j];
  #pragma unroll
  for (int k = 0; k < 15; k++) acc += xs[k] * enc_w[k*128 + j];
  h[(size_t)n*128 + j] = fmaxf(acc, 0.0f);
}

// ================= SGEMM: C[M][ldb] = A[M][128] * B[128][ldb] =================
// 128x128 block tile, 8x8 register micro-tile, BK=16.
// mode 0: plain store (ldb==128). mode 1: bias+relu (ldb==160).
#define BK 16
__global__ __launch_bounds__(256) void gemm_kernel(
    const float* __restrict__ A, const float* __restrict__ B, float* __restrict__ C,
    int M, int ldb, int mode, const float* __restrict__ bias){
  __shared__ float As[BK][128+4];
  __shared__ float Bs[BK][128];
  int t = threadIdx.x;
  int tx = t & 15, ty = t >> 4;
  int n0 = blockIdx.x * 128;
  int j0 = blockIdx.y * 128;
  float acc[8][8];
  #pragma unroll
  for (int i = 0; i < 8; i++)
    #pragma unroll
    for (int j = 0; j < 8; j++) acc[i][j] = 0.0f;

  for (int kb = 0; kb < 128; kb += BK){
    #pragma unroll
    for (int q = 0; q < 2; q++){
      int v = t*2 + q;                 // 0..511
      int row = v >> 2, c4 = v & 3;
      int gn = n0 + row;
      float4 f = make_float4(0,0,0,0);
      if (gn < M) f = *(const float4*)(A + (size_t)gn*128 + kb + c4*4);
      As[c4*4+0][row] = f.x; As[c4*4+1][row] = f.y;
      As[c4*4+2][row] = f.z; As[c4*4+3][row] = f.w;
    }
    #pragma unroll
    for (int q = 0; q < 2; q++){
      int v = t*2 + q;
      int kk = v >> 5, j4 = v & 31;
      int gj = j0 + j4*4;
      float4 f = make_float4(0,0,0,0);
      if (gj < ldb) f = *(const float4*)(B + (size_t)(kb+kk)*ldb + gj);
      *(float4*)&Bs[kk][j4*4] = f;
    }
    __syncthreads();
    #pragma unroll
    for (int kk = 0; kk < BK; kk++){
      float4 a0 = *(const float4*)&As[kk][ty*8];
      float4 a1 = *(const float4*)&As[kk][ty*8+4];
      float4 b0 = *(const float4*)&Bs[kk][tx*8];
      float4 b1 = *(const float4*)&Bs[kk][tx*8+4];
      float av[8] = {a0.x,a0.y,a0.z,a0.w,a1.x,a1.y,a1.z,a1.w};
      float bv[8] = {b0.x,b0.y,b0.z,b0.w,b1.x,b1.y,b1.z,b1.w};
      #pragma unroll
      for (int i = 0; i < 8; i++)
        #pragma unroll
        for (int j = 0; j < 8; j++) acc[i][j] += av[i]*bv[j];
    }
    __syncthreads();
  }

  int jb = j0 + tx*8;
  bool jok = jb < ldb;                 // ldb multiple of 8
  float bi[8];
  if (mode && jok){
    #pragma unroll
    for (int jj = 0; jj < 8; jj++) bi[jj] = bias[jb+jj];
  }
  #pragma unroll
  for (int i = 0; i < 8; i++){
    int gn = n0 + ty*8 + i;
    if (gn < M && jok){
      float o[8];
      #pragma unroll
      for (int jj = 0; jj < 8; jj++){
        float v = acc[i][jj];
        if (mode) v = fmaxf(v + bi[jj], 0.0f);
        o[jj] = v;
      }
      *(float4*)(C + (size_t)gn*ldb + jb)     = make_float4(o[0],o[1],o[2],o[3]);
      *(float4*)(C + (size_t)gn*ldb + jb + 4) = make_float4(o[4],o[5],o[6],o[7]);
    }
  }
}

// ================= a_s/a_d per (node, head) =================
__global__ void asad_kernel(const float* __restrict__ hp, const float* __restrict__ att_src,
                            const float* __restrict__ att_dst, float* __restrict__ a_s, float* __restrict__ a_d){
  int t = blockIdx.x*256 + threadIdx.x;
  if (t >= N_NODES*4) return;
  int n = t >> 2, hh = t & 3;
  const float* hpr = hp + (size_t)n*128 + hh*32;
  const float* as = att_src + hh*32;
  const float* ad = att_dst + hh*32;
  float s = 0, d = 0;
  #pragma unroll
  for (int q = 0; q < 32; q++){ float v = hpr[q]; s += v*as[q]; d += v*ad[q]; }
  a_s[t] = s; a_d[t] = d;
}

// ================= per-edge a_e = ea @ M[l]  (E+N rows) =================
__global__ void ae_kernel(const void* __restrict__ ea_raw, const int* __restrict__ mode,
                          const float* __restrict__ ea_self, const float* __restrict__ Mmat_l,
                          float* __restrict__ ae){
  int e = blockIdx.x*256 + threadIdx.x;
  if (e >= TOT_E) return;
  int m = mode[0];
  float v[10];
  if (e < N_EDGES){
    #pragma unroll
    for (int k = 0; k < 10; k++) v[k] = ldm(ea_raw, (long)e*10 + k, m);
  } else {
    const float* p = ea_self + (size_t)(e - N_EDGES)*10;
    #pragma unroll
    for (int k = 0; k < 10; k++) v[k] = p[k];
  }
  #pragma unroll
  for (int hh = 0; hh < 4; hh++){
    float s = 0;
    #pragma unroll
    for (int k = 0; k < 10; k++) s += v[k]*Mmat_l[k*4 + hh];
    ae[(size_t)e*4 + hh] = s;
  }
}

// ================= softmax attention per (dst, head), explicit segment-max =================
__global__ void attn_kernel(const float* __restrict__ a_s, const float* __restrict__ a_d,
                            const float* __restrict__ ae, const int* __restrict__ srcs,
                            const int* __restrict__ eid, const int* __restrict__ rowptr,
                            float* __restrict__ attn){
  int t = blockIdx.x*256 + threadIdx.x;
  if (t >= N_NODES*4) return;
  int d = t >> 2, hh = t & 3;
  int p0 = rowptr[d], p1 = rowptr[d+1];
  float ad = a_d[d*4 + hh];
  float mx = -3.4e38f;
  for (int p = p0; p < p1; p++){
    float al = a_s[srcs[p]*4 + hh] + ad + ae[(size_t)eid[p]*4 + hh];
    al = (al > 0.0f) ? al : 0.2f*al;          // leaky_relu 0.2
    attn[(size_t)p*4 + hh] = al;
    mx = fmaxf(mx, al);
  }
  float sum = 0;
  for (int p = p0; p < p1; p++){
    float w = expf(attn[(size_t)p*4 + hh] - mx);
    attn[(size_t)p*4 + hh] = w; sum += w;
  }
  float inv = 1.0f / sum;                      // self-loop guarantees sum>0
  for (int p = p0; p < p1; p++) attn[(size_t)p*4 + hh] *= inv;
}

// ================= aggregate + bias + residual + LayerNorm (in-place h) =================
__global__ __launch_bounds__(128) void aggregate_kernel(
    const float* __restrict__ hp, const float* __restrict__ attn, const int* __restrict__ srcs,
    const int* __restrict__ rowptr, const float* __restrict__ bias_l,
    const float* __restrict__ ln_g_l, const float* __restrict__ ln_b_l, float* __restrict__ h){
  int d = blockIdx.x, j = threadIdx.x;
  int p0 = rowptr[d], p1 = rowptr[d+1];
  int hsel = j >> 5;
  float acc = 0;
  for (int p = p0; p < p1; p++){
    int s = srcs[p];
    acc += attn[(size_t)p*4 + hsel] * hp[(size_t)s*128 + j];
  }
  float v = acc + bias_l[j] + h[(size_t)d*128 + j];
  float s = v, sq = v*v;
  #pragma unroll
  for (int off = 32; off >= 1; off >>= 1){ s += __shfl_xor(s, off); sq += __shfl_xor(sq, off); }
  __shared__ float red[4];
  int w = j >> 6;
  if ((j & 63) == 0){ red[w*2] = s; red[w*2+1] = sq; }
  __syncthreads();
  float ts = red[0] + red[2], tq = red[1] + red[3];
  float mu  = ts * (1.0f/128.0f);
  float var = tq * (1.0f/128.0f) - mu*mu;
  float rs  = rsqrtf(fmaxf(var, 0.0f) + 1e-5f);
  h[(size_t)d*128 + j] = (v - mu)*rs*ln_g_l[j] + ln_b_l[j];
}

// ================= pooling partials =================
__global__ __launch_bounds__(128) void pool_kernel(const float* __restrict__ h,
                                                   float* __restrict__ pool_sum,
                                                   unsigned* __restrict__ pool_maxenc){
  int j = threadIdx.x;
  int chunk = (N_NODES + gridDim.x - 1) / gridDim.x;
  int nb = blockIdx.x*chunk, ne = min(nb + chunk, N_NODES);
  if (nb >= ne) return;
  float s = 0, m = -3.4e38f;
  for (int n = nb; n < ne; n++){ float v = h[(size_t)n*128 + j]; s += v; m = fmaxf(m, v); }
  atomicAdd(&pool_sum[j], s);
  atomicMax(&pool_maxenc[j], fenc(m));
}

// ================= pooled MLP + global head (f32 out) =================
__global__ __launch_bounds__(128) void global_kernel(
    const float* __restrict__ pool_sum, const unsigned* __restrict__ pool_maxenc,
    const float* __restrict__ u, const float* __restrict__ pool_w, const float* __restrict__ pool_b,
    const float* __restrict__ pool_ln_g, const float* __restrict__ pool_ln_b,
    const float* __restrict__ glob_w1, const float* __restrict__ glob_b1,
    const float* __restrict__ glob_w2, const float* __restrict__ glob_b2, float* __restrict__ out_glob){
  __shared__ float pooled[392];
  __shared__ float gv[8];
  __shared__ float t1[32];
  __shared__ float mv[2];
  int t = threadIdx.x;
  for (int i = t; i < 392; i += 128){
    float v;
    if (i < 128)      v = pool_sum[i] * (1.0f/(float)N_NODES);
    else if (i < 256) v = fdec(pool_maxenc[i-128]);
    else if (i < 384) v = pool_sum[i-256];
    else              v = u[i-384];
    pooled[i] = v;
  }
  __syncthreads();
  if (t < 8){
    float acc = pool_b[t];
    for (int f = 0; f < 392; f++) acc += pooled[f]*pool_w[f*8 + t];
    gv[t] = fmaxf(acc, 0.0f);
  }
  __syncthreads();
  if (t == 0){
    float mu = 0; for (int i = 0; i < 8; i++) mu += gv[i];
    mu *= 0.125f;
    float var = 0; for (int i = 0; i < 8; i++){ float d = gv[i]-mu; var += d*d; }
    var *= 0.125f;
    mv[0] = mu; mv[1] = rsqrtf(var + 1e-5f);
  }
  __syncthreads();
  float gnorm = (t < 8) ? (gv[t]-mv[0])*mv[1]*pool_ln_g[t] + pool_ln_b[t] : 0.0f;
  __syncthreads();
  if (t < 8) gv[t] = gnorm;
  __syncthreads();
  if (t < 32){
    float acc = glob_b1[t];
    for (int q = 0; q < 8; q++) acc += gv[q]*glob_w1[q*32 + t];
    t1[t] = fmaxf(acc, 0.0f);
  }
  __syncthreads();
  if (t < 4){
    float acc = glob_b2[t];
    for (int m = 0; m < 32; m++) acc += t1[m]*glob_w2[m*4 + t];
    out_glob[t] = tanhf(acc);
  }
}

// ================= finalize: heads + strategies, one thread per node (f32 out) =================
__global__ void finalize_kernel(
    const float* __restrict__ z, const float* __restrict__ head_w2, const float* __restrict__ head_b2,
    const float* __restrict__ strat_w2, const float* __restrict__ strat_b2, float* __restrict__ out){
  int n = blockIdx.x*256 + threadIdx.x;
  if (n >= N_NODES) return;
  const float* zr = z + (size_t)n*160;
  float y[4];
  #pragma unroll
  for (int k = 0; k < 4; k++){
    float acc = head_b2[k];
    #pragma unroll
    for (int m = 0; m < 32; m++) acc += zr[k*32+m]*head_w2[k*32+m];
    y[k] = acc;
  }
  out[n]             = tanhf(y[0]);                       // priority
  out[N_NODES + n]   = 1.0f/(1.0f + expf(-y[1]));         // cooperation
  out[2*N_NODES + n] = 1.0f/(1.0f + expf(-y[2]));         // urgency
  out[3*N_NODES + n] = 1.0f/(1.0f + expf(-y[3]));         // safety
  float sv[5], mx = -3.4e38f;
  #pragma unroll
  for (int j = 0; j < 5; j++){
    float acc = strat_b2[j];
    #pragma unroll
    for (int m = 0; m < 32; m++) acc += zr[128+m]*strat_w2[m*5+j];
    sv[j] = acc; mx = fmaxf(mx, acc);
  }
  float se = 0;
  #pragma unroll
  for (int j = 0; j < 5; j++){ sv[j] = expf(sv[j]-mx); se += sv[j]; }
  float inv = 1.0f/se;
  #pragma unroll
  for (int j = 0; j < 5; j++) out[4*N_NODES + (size_t)n*5 + j] = sv[j]*inv;
}

// ======================================================================
extern "C" void kernel_launch(void* const* d_in, const int* in_sizes, int n_in,
                              void* d_out, int out_size, void* d_ws, size_t ws_size,
                              hipStream_t stream){
  float* out = (float*)d_out;   // reference output dtype is float32

  static const int exp_sizes[30] = {
    750000, 1200000, 6000000, 8, 1920, 128, 49152, 384, 384, 3840, 384,
    384, 384, 384, 3136, 8, 8, 8, 16384, 128, 128, 4, 4096, 32, 160, 5,
    256, 32, 128, 4 };
  int host_code = 0;
  if (n_in != 30){
    int nn = n_in < 0 ? 0 : (n_in > 63 ? 63 : n_in);
    host_code = 4096 + 32*nn;
  } else {
    for (int i = 0; i < 30; i++)
      if (in_sizes[i] != exp_sizes[i]){ host_code = 1024 + 8*i; break; }
  }
  if (!host_code && out_size != 9*N_NODES + 4) host_code = 12288;
  if (host_code){
    sentinel_kernel<<<1, 64, 0, stream>>>(host_code, nullptr, nullptr, out);
    return;
  }

  const int* ei = (const int*)d_in[1];

  char* wsp = (char*)d_ws;
  size_t off = 0;
  auto alloc = [&](size_t bytes)->char*{ char* p = wsp + off; off += (bytes + 255) & ~(size_t)255; return p; };

  float* h      = (float*)alloc((size_t)N_NODES*128*4);   // 25.6 MB
  float* hp     = (float*)alloc((size_t)N_NODES*128*4);   // 25.6 MB
  float* a_s    = (float*)alloc((size_t)N_NODES*4*4);
  float* a_d    = (float*)alloc((size_t)N_NODES*4*4);
  float* ae     = (float*)alloc((size_t)TOT_E*4*4);       // 10.4 MB
  float* attn   = (float*)alloc((size_t)TOT_E*4*4);       // 10.4 MB
  // z[N][160] = 32 MB aliases hp(25.6)+a_s+a_d+head of ae — all dead before heads GEMM
  float* zbuf   = hp;
  int*   srcs   = (int*)alloc((size_t)TOT_E*4);
  int*   eid    = (int*)alloc((size_t)TOT_E*4);
  int*   rowptr = (int*)alloc((size_t)(N_NODES+1)*4);

  const int SN = 27;
  static const int sn_sizes[SN] = {
    8, 1920, 128, 49152, 384, 384, 3840, 384, 384, 384, 384,
    3136, 8, 8, 8, 16384, 128, 128, 4, 4096, 32, 160, 5, 256, 32, 128, 4 };
  static const int sn_input[SN] = {
    3, 4, 5, 6, 7, 8, 9, 10, 11, 12, 13, 14, 15, 16, 17,
    18, 19, 20, 21, 22, 23, 24, 25, 26, 27, 28, 29 };
  float* sarr[SN];
  for (int i = 0; i < SN; i++) sarr[i] = (float*)alloc((size_t)sn_sizes[i]*4);
  float* u_c       = sarr[0];
  float* enc_w_c   = sarr[1];
  float* enc_b_c   = sarr[2];
  float* Wl        = sarr[3];
  float* att_src_c = sarr[4];
  float* att_dst_c = sarr[5];
  float* lin_e_c   = sarr[6];
  float* att_e_c   = sarr[7];
  float* bias_c    = sarr[8];
  float* ln_g_c    = sarr[9];
  float* ln_b_c    = sarr[10];
  float* pool_w_c  = sarr[11];
  float* pool_b_c  = sarr[12];
  float* pln_g_c   = sarr[13];
  float* pln_b_c   = sarr[14];
  float* head_w1_c = sarr[15];
  float* head_b1_c = sarr[16];
  float* head_w2_c = sarr[17];
  float* head_b2_c = sarr[18];
  float* strat_w1_c= sarr[19];
  float* strat_b1_c= sarr[20];
  float* strat_w2_c= sarr[21];
  float* strat_b2_c= sarr[22];
  float* glob_w1_c = sarr[23];
  float* glob_b1_c = sarr[24];
  float* glob_w2_c = sarr[25];
  float* glob_b2_c = sarr[26];

  float* W1cat  = (float*)alloc((size_t)128*160*4);
  float* b1cat  = (float*)alloc(160*4);
  float* Mmat   = (float*)alloc(3*40*4);
  int*   mode   = (int*)alloc(256);
  size_t zero_begin = off;
  int*      devflags    = (int*)alloc(256);
  int*      cnt         = (int*)alloc((size_t)N_NODES*4);
  int*      fill        = (int*)alloc((size_t)N_NODES*4);
  float*    ea_sum      = (float*)alloc((size_t)N_NODES*10*4);
  float*    pool_sum    = (float*)alloc(128*4);
  unsigned* pool_maxenc = (unsigned*)alloc(128*4);
  size_t zero_bytes = off - zero_begin;

  if (ws_size < off){
    sentinel_kernel<<<1, 64, 0, stream>>>(8192, nullptr, nullptr, out);
    return;
  }

  hipMemsetAsync(wsp + zero_begin, 0, zero_bytes, stream);

  detect_kernel<<<1, 256, 0, stream>>>(d_in[4], mode);
  check_ei_kernel<<<(2*N_EDGES + 255)/256, 256, 0, stream>>>(ei, devflags);

  CvtTab tab;
  for (int i = 0; i < SN; i++){ tab.s[i] = d_in[sn_input[i]]; tab.d[i] = sarr[i]; tab.n[i] = sn_sizes[i]; }
  cvt_small_kernel<<<SN, 256, 0, stream>>>(tab, mode);

  pack_kernel<<<(128*160 + 255)/256, 256, 0, stream>>>(head_w1_c, strat_w1_c, head_b1_c, strat_b1_c, W1cat, b1cat);
  mmat_kernel<<<1, 128, 0, stream>>>(lin_e_c, att_e_c, Mmat);
  count_kernel<<<(N_EDGES + 255)/256, 256, 0, stream>>>(ei, d_in[2], mode, cnt, ea_sum);
  rowptr_kernel<<<1, 1024, 0, stream>>>(cnt, rowptr);
  selfdiv_kernel<<<(N_NODES*10 + 255)/256, 256, 0, stream>>>(cnt, ea_sum);
  scatter_kernel<<<(TOT_E + 255)/256, 256, 0, stream>>>(ei, rowptr, fill, srcs, eid);
  encoder_kernel<<<N_NODES, 128, 0, stream>>>(d_in[0], mode, enc_w_c, enc_b_c, h);

  const int gx = (N_NODES + 127)/128;   // 391
  for (int l = 0; l < NLAYER; l++){
    ae_kernel<<<(TOT_E + 255)/256, 256, 0, stream>>>(d_in[2], mode, ea_sum, Mmat + l*40, ae);
    gemm_kernel<<<dim3(gx, 1), 256, 0, stream>>>(h, Wl + (size_t)l*128*128, hp, N_NODES, 128, 0, nullptr);
    asad_kernel<<<(N_NODES*4 + 255)/256, 256, 0, stream>>>(hp, att_src_c + l*128, att_dst_c + l*128, a_s, a_d);
    attn_kernel<<<(N_NODES*4 + 255)/256, 256, 0, stream>>>(a_s, a_d, ae, srcs, eid, rowptr, attn);
    aggregate_kernel<<<N_NODES, 128, 0, stream>>>(hp, attn, srcs, rowptr,
                                                  bias_c + l*128, ln_g_c + l*128, ln_b_c + l*128, h);
  }

  pool_kernel<<<256, 128, 0, stream>>>(h, pool_sum, pool_maxenc);
  global_kernel<<<1, 128, 0, stream>>>(pool_sum, pool_maxenc, u_c, pool_w_c, pool_b_c, pln_g_c, pln_b_c,
                                       glob_w1_c, glob_b1_c, glob_w2_c, glob_b2_c, out + 9*N_NODES);
  gemm_kernel<<<dim3(gx, 2), 256, 0, stream>>>(h, W1cat, zbuf, N_NODES, 160, 1, b1cat);
  finalize_kernel<<<(N_NODES + 255)/256, 256, 0, stream>>>(zbuf, head_w2_c, head_b2_c, strat_w2_c, strat_b2_c, out);
  sentinel_kernel<<<1, 64, 0, stream>>>(0, devflags, mode, out);
}

// Round 5
// 953.645 us; speedup vs baseline: 1.3682x; 1.3682x over previous
//
#include <hip/hip_runtime.h>
#include <hip/hip_bf16.h>

#define N_NODES 50000
#define N_EDGES 600000
#define TOT_E   (N_EDGES + N_NODES)   // 650000 with self loops
#define NLAYER  3
#define PB      200                   // pool partial blocks (50000/250)

typedef __hip_bfloat16 bf16;
__device__ __forceinline__ float b2f(bf16 v){ return __bfloat162float(v); }

// dual-mode load: m=1 -> f32, m=0 -> bf16
__device__ __forceinline__ float ldm(const void* p, long i, int m){
  return m ? ((const float*)p)[i] : b2f(((const bf16*)p)[i]);
}

// ================= input dtype detection =================
__global__ void detect_kernel(const void* probe, int* mode){
  __shared__ float red[256];
  int t = threadIdx.x;
  const bf16* p = (const bf16*)probe;
  float mx = 0.f;
  for (int i = t; i < 1920; i += 256){
    float v = fabsf(b2f(p[i]));
    if (!isfinite(v)) v = 1e30f;
    mx = fmaxf(mx, v);
  }
  red[t] = mx; __syncthreads();
  if (t == 0){
    float m = 0.f;
    for (int i = 0; i < 256; i++) m = fmaxf(m, red[i]);
    mode[0] = (m > 1000.0f) ? 1 : 0;
  }
}

// ================= edge_index sanity =================
__global__ void check_ei_kernel(const int* __restrict__ ei, int* devflags){
  int t = blockIdx.x*256 + threadIdx.x;
  if (t < 2*N_EDGES){
    int v = ei[t];
    if (v < 0 || v >= N_NODES) atomicOr(&devflags[0], 1);
  }
  if (t < 1024){
    if (ei[2*t + 1] == 0) atomicAdd(&devflags[1], 1);
  }
}

// ================= sentinel (f32 output) =================
__global__ void sentinel_kernel(int host_code, const int* devflags, const int* mode, float* out){
  if (threadIdx.x == 0 && blockIdx.x == 0){
    int code = host_code;
    if (!code && devflags){
      if (devflags[1] > 900)      code = 16384;
      else if (devflags[0])       code = 20480;
    }
    if (code){
      if (mode) code += 512*mode[0];
      out[0] = (float)code;
    }
  }
}

// ================= small weight conversion =================
struct CvtTab { const void* s[27]; float* d[27]; int n[27]; };
__global__ void cvt_small_kernel(CvtTab tab, const int* mode){
  int b = blockIdx.x;
  int m = mode[0];
  const void* s = tab.s[b]; float* d = tab.d[b]; int n = tab.n[b];
  for (int i = threadIdx.x; i < n; i += 256) d[i] = ldm(s, i, m);
}

// ================= CSR build (int atomics only) =================
__global__ void count_kernel(const int* __restrict__ ei, int* __restrict__ cnt){
  int e = blockIdx.x*256 + threadIdx.x;
  if (e >= N_EDGES) return;
  atomicAdd(&cnt[ei[N_EDGES + e]], 1);
}

__global__ __launch_bounds__(1024) void rowptr_kernel(const int* __restrict__ cnt, int* __restrict__ rowptr){
  __shared__ int part[1024];
  int t = threadIdx.x;
  const int CH = (N_NODES + 1023)/1024;        // 49
  int b = t*CH, e = min(b+CH, N_NODES);
  int loc = 0;
  for (int i = b; i < e; i++) loc += cnt[i] + 1;   // +1 self loop
  part[t] = loc;
  __syncthreads();
  if (t == 0){
    int run = 0;
    for (int i = 0; i < 1024; i++){ int tmp = part[i]; part[i] = run; run += tmp; }
    rowptr[N_NODES] = run;
  }
  __syncthreads();
  int run = part[t];
  for (int i = b; i < e; i++){ rowptr[i] = run; run += cnt[i] + 1; }
}

__global__ void scatter_kernel(const int* __restrict__ ei, const int* __restrict__ rowptr,
                               int* __restrict__ fill, int* __restrict__ srcs, int* __restrict__ eid){
  int e = blockIdx.x*256 + threadIdx.x;
  if (e >= TOT_E) return;
  if (e < N_EDGES){
    int s = ei[e], d = ei[N_EDGES + e];
    int pos = rowptr[d] + atomicAdd(&fill[d], 1);
    srcs[pos] = s; eid[pos] = e;
  } else {
    int i = e - N_EDGES;
    int pos = rowptr[i+1] - 1;                 // reserved last slot = self loop
    srcs[pos] = i; eid[pos] = e;
  }
}

// ================= weight packing =================
__global__ void pack_kernel(const float* __restrict__ head_w1, const float* __restrict__ strat_w1,
                            const float* __restrict__ head_b1, const float* __restrict__ strat_b1,
                            float* __restrict__ W1cat, float* __restrict__ b1cat){
  int t = blockIdx.x*256 + threadIdx.x;
  if (t < 128*160){
    int f = t / 160, c = t % 160;
    W1cat[t] = (c < 128) ? head_w1[(c>>5)*4096 + f*32 + (c&31)]
                         : strat_w1[f*32 + (c-128)];
  }
  if (t < 160) b1cat[t] = (t < 128) ? head_b1[t] : strat_b1[t-128];
}

// M[l][k][h] = sum_d We[l][k][h*32+d] * att_edge[l][h][d]
__global__ void mmat_kernel(const float* __restrict__ We, const float* __restrict__ att_edge,
                            float* __restrict__ M){
  int t = threadIdx.x;
  if (t >= 120) return;
  int l = t / 40, r = t % 40, k = r / 4, hh = r % 4;
  float s = 0;
  #pragma unroll
  for (int d = 0; d < 32; d++)
    s += We[l*1280 + k*128 + hh*32 + d] * att_edge[l*128 + hh*32 + d];
  M[t] = s;
}

// ================= encoder (dual-mode x) =================
__global__ __launch_bounds__(128) void encoder_kernel(const void* __restrict__ x_raw, const int* __restrict__ mode,
                                                      const float* __restrict__ enc_w, const float* __restrict__ enc_b,
                                                      float* __restrict__ h){
  __shared__ float xs[16];
  int n = blockIdx.x, j = threadIdx.x;
  if (j < 15) xs[j] = ldm(x_raw, (long)n*15 + j, mode[0]);
  __syncthreads();
  float acc = enc_b[j];
  #pragma unroll
  for (int k = 0; k < 15; k++) acc += xs[k] * enc_w[k*128 + j];
  h[(size_t)n*128 + j] = fmaxf(acc, 0.0f);
}

// ================= SGEMM: C[M][ldb] = A[M][128] * B[128][ldb] =================
#define BK 16
__global__ __launch_bounds__(256) void gemm_kernel(
    const float* __restrict__ A, const float* __restrict__ B, float* __restrict__ C,
    int M, int ldb, int mode, const float* __restrict__ bias){
  __shared__ float As[BK][128+4];
  __shared__ float Bs[BK][128];
  int t = threadIdx.x;
  int tx = t & 15, ty = t >> 4;
  int n0 = blockIdx.x * 128;
  int j0 = blockIdx.y * 128;
  float acc[8][8];
  #pragma unroll
  for (int i = 0; i < 8; i++)
    #pragma unroll
    for (int j = 0; j < 8; j++) acc[i][j] = 0.0f;

  for (int kb = 0; kb < 128; kb += BK){
    #pragma unroll
    for (int q = 0; q < 2; q++){
      int v = t*2 + q;
      int row = v >> 2, c4 = v & 3;
      int gn = n0 + row;
      float4 f = make_float4(0,0,0,0);
      if (gn < M) f = *(const float4*)(A + (size_t)gn*128 + kb + c4*4);
      As[c4*4+0][row] = f.x; As[c4*4+1][row] = f.y;
      As[c4*4+2][row] = f.z; As[c4*4+3][row] = f.w;
    }
    #pragma unroll
    for (int q = 0; q < 2; q++){
      int v = t*2 + q;
      int kk = v >> 5, j4 = v & 31;
      int gj = j0 + j4*4;
      float4 f = make_float4(0,0,0,0);
      if (gj < ldb) f = *(const float4*)(B + (size_t)(kb+kk)*ldb + gj);
      *(float4*)&Bs[kk][j4*4] = f;
    }
    __syncthreads();
    #pragma unroll
    for (int kk = 0; kk < BK; kk++){
      float4 a0 = *(const float4*)&As[kk][ty*8];
      float4 a1 = *(const float4*)&As[kk][ty*8+4];
      float4 b0 = *(const float4*)&Bs[kk][tx*8];
      float4 b1 = *(const float4*)&Bs[kk][tx*8+4];
      float av[8] = {a0.x,a0.y,a0.z,a0.w,a1.x,a1.y,a1.z,a1.w};
      float bv[8] = {b0.x,b0.y,b0.z,b0.w,b1.x,b1.y,b1.z,b1.w};
      #pragma unroll
      for (int i = 0; i < 8; i++)
        #pragma unroll
        for (int j = 0; j < 8; j++) acc[i][j] += av[i]*bv[j];
    }
    __syncthreads();
  }

  int jb = j0 + tx*8;
  bool jok = jb < ldb;
  float bi[8];
  if (mode && jok){
    #pragma unroll
    for (int jj = 0; jj < 8; jj++) bi[jj] = bias[jb+jj];
  }
  #pragma unroll
  for (int i = 0; i < 8; i++){
    int gn = n0 + ty*8 + i;
    if (gn < M && jok){
      float o[8];
      #pragma unroll
      for (int jj = 0; jj < 8; jj++){
        float v = acc[i][jj];
        if (mode) v = fmaxf(v + bi[jj], 0.0f);
        o[jj] = v;
      }
      *(float4*)(C + (size_t)gn*ldb + jb)     = make_float4(o[0],o[1],o[2],o[3]);
      *(float4*)(C + (size_t)gn*ldb + jb + 4) = make_float4(o[4],o[5],o[6],o[7]);
    }
  }
}

// ================= a_s/a_d per (node, head) =================
__global__ void asad_kernel(const float* __restrict__ hp, const float* __restrict__ att_src,
                            const float* __restrict__ att_dst, float* __restrict__ a_s, float* __restrict__ a_d){
  int t = blockIdx.x*256 + threadIdx.x;
  if (t >= N_NODES*4) return;
  int n = t >> 2, hh = t & 3;
  const float* hpr = hp + (size_t)n*128 + hh*32;
  const float* as = att_src + hh*32;
  const float* ad = att_dst + hh*32;
  float s = 0, d = 0;
  #pragma unroll
  for (int q = 0; q < 32; q++){ float v = hpr[q]; s += v*as[q]; d += v*ad[q]; }
  a_s[t] = s; a_d[t] = d;
}

// ================= per-edge a_e = ea @ M[l]  (real edges only) =================
__global__ void ae_kernel(const void* __restrict__ ea_raw, const int* __restrict__ mode,
                          const float* __restrict__ Mmat_l, float* __restrict__ ae){
  int e = blockIdx.x*256 + threadIdx.x;
  if (e >= N_EDGES) return;
  int m = mode[0];
  float v[10];
  #pragma unroll
  for (int k = 0; k < 10; k++) v[k] = ldm(ea_raw, (long)e*10 + k, m);
  #pragma unroll
  for (int hh = 0; hh < 4; hh++){
    float s = 0;
    #pragma unroll
    for (int k = 0; k < 10; k++) s += v[k]*Mmat_l[k*4 + hh];
    ae[(size_t)e*4 + hh] = s;
  }
}

// ================= softmax attention; self-loop a_e = mean of real-edge a_e =================
// (fill_value='mean' self attr is linear through ea@M, so mean commutes)
__global__ void attn_kernel(const float* __restrict__ a_s, const float* __restrict__ a_d,
                            const float* __restrict__ ae, const int* __restrict__ srcs,
                            const int* __restrict__ eid, const int* __restrict__ rowptr,
                            float* __restrict__ attn){
  int t = blockIdx.x*256 + threadIdx.x;
  if (t >= N_NODES*4) return;
  int d = t >> 2, hh = t & 3;
  int p0 = rowptr[d], p1 = rowptr[d+1];
  int nreal = p1 - p0 - 1;
  float ad = a_d[d*4 + hh];
  float mx = -3.4e38f, ssum = 0.f;
  for (int p = p0; p < p1-1; p++){
    float aev = ae[(size_t)eid[p]*4 + hh];
    ssum += aev;
    float al = a_s[srcs[p]*4 + hh] + ad + aev;
    al = (al > 0.0f) ? al : 0.2f*al;          // leaky_relu 0.2
    attn[(size_t)p*4 + hh] = al;
    mx = fmaxf(mx, al);
  }
  float aself = ssum / (float)max(nreal, 1);
  float als = a_s[d*4 + hh] + ad + aself;
  als = (als > 0.0f) ? als : 0.2f*als;
  mx = fmaxf(mx, als);
  float sum = 0;
  for (int p = p0; p < p1-1; p++){
    float w = expf(attn[(size_t)p*4 + hh] - mx);
    attn[(size_t)p*4 + hh] = w; sum += w;
  }
  float ws = expf(als - mx); sum += ws;
  float inv = 1.0f / sum;
  for (int p = p0; p < p1-1; p++) attn[(size_t)p*4 + hh] *= inv;
  attn[(size_t)(p1-1)*4 + hh] = ws*inv;
}

// ================= aggregate + bias + residual + LayerNorm: one wave per node =================
__global__ __launch_bounds__(256) void aggregate_kernel(
    const float* __restrict__ hp, const float* __restrict__ attn, const int* __restrict__ srcs,
    const int* __restrict__ rowptr, const float* __restrict__ bias_l,
    const float* __restrict__ ln_g_l, const float* __restrict__ ln_b_l, float* __restrict__ h){
  int n = blockIdx.x*4 + (threadIdx.x >> 6);
  int lane = threadIdx.x & 63;
  int p0 = rowptr[n], p1 = rowptr[n+1];
  int hsel = lane >> 4;                        // head of cols {2*lane, 2*lane+1}
  float a0 = 0, a1 = 0;
  for (int p = p0; p < p1; p++){
    int s = srcs[p];
    float w = attn[(size_t)p*4 + hsel];
    float2 hv = *(const float2*)(hp + (size_t)s*128 + lane*2);
    a0 += w*hv.x; a1 += w*hv.y;
  }
  float2 res = *(const float2*)(h + (size_t)n*128 + lane*2);
  float2 bi  = *(const float2*)(bias_l + lane*2);
  float v0 = a0 + bi.x + res.x;
  float v1 = a1 + bi.y + res.y;
  float s = v0 + v1, sq = v0*v0 + v1*v1;
  #pragma unroll
  for (int off = 32; off >= 1; off >>= 1){ s += __shfl_xor(s, off); sq += __shfl_xor(sq, off); }
  float mu  = s * (1.0f/128.0f);
  float var = sq * (1.0f/128.0f) - mu*mu;
  float rs  = rsqrtf(fmaxf(var, 0.0f) + 1e-5f);
  float2 g  = *(const float2*)(ln_g_l + lane*2);
  float2 bb = *(const float2*)(ln_b_l + lane*2);
  float2 o;
  o.x = (v0 - mu)*rs*g.x + bb.x;
  o.y = (v1 - mu)*rs*g.y + bb.y;
  *(float2*)(h + (size_t)n*128 + lane*2) = o;
}

// ================= pooling partials (no atomics, deterministic) =================
__global__ __launch_bounds__(128) void pool_part_kernel(const float* __restrict__ h,
                                                        float* __restrict__ psum, float* __restrict__ pmax){
  int b = blockIdx.x, j = threadIdx.x;
  int nb = b*(N_NODES/PB), ne = nb + (N_NODES/PB);
  float s = 0, m = -3.4e38f;
  for (int n = nb; n < ne; n++){ float v = h[(size_t)n*128 + j]; s += v; m = fmaxf(m, v); }
  psum[b*128 + j] = s; pmax[b*128 + j] = m;
}

// ================= pooled MLP + global head (f32 out) =================
__global__ __launch_bounds__(128) void global_kernel(
    const float* __restrict__ psum, const float* __restrict__ pmax,
    const float* __restrict__ u, const float* __restrict__ pool_w, const float* __restrict__ pool_b,
    const float* __restrict__ pool_ln_g, const float* __restrict__ pool_ln_b,
    const float* __restrict__ glob_w1, const float* __restrict__ glob_b1,
    const float* __restrict__ glob_w2, const float* __restrict__ glob_b2, float* __restrict__ out_glob){
  __shared__ float pooled[392];
  __shared__ float gv[8];
  __shared__ float t1[32];
  __shared__ float mv[2];
  int t = threadIdx.x;
  float s = 0, m = -3.4e38f;
  for (int b = 0; b < PB; b++){ s += psum[b*128 + t]; m = fmaxf(m, pmax[b*128 + t]); }
  pooled[t]       = s * (1.0f/(float)N_NODES);
  pooled[128 + t] = m;
  pooled[256 + t] = s;
  if (t < 8) pooled[384 + t] = u[t];
  __syncthreads();
  if (t < 8){
    float acc = pool_b[t];
    for (int f = 0; f < 392; f++) acc += pooled[f]*pool_w[f*8 + t];
    gv[t] = fmaxf(acc, 0.0f);
  }
  __syncthreads();
  if (t == 0){
    float mu = 0; for (int i = 0; i < 8; i++) mu += gv[i];
    mu *= 0.125f;
    float var = 0; for (int i = 0; i < 8; i++){ float d = gv[i]-mu; var += d*d; }
    var *= 0.125f;
    mv[0] = mu; mv[1] = rsqrtf(var + 1e-5f);
  }
  __syncthreads();
  float gnorm = (t < 8) ? (gv[t]-mv[0])*mv[1]*pool_ln_g[t] + pool_ln_b[t] : 0.0f;
  __syncthreads();
  if (t < 8) gv[t] = gnorm;
  __syncthreads();
  if (t < 32){
    float acc = glob_b1[t];
    for (int q = 0; q < 8; q++) acc += gv[q]*glob_w1[q*32 + t];
    t1[t] = fmaxf(acc, 0.0f);
  }
  __syncthreads();
  if (t < 4){
    float acc = glob_b2[t];
    for (int mm = 0; mm < 32; mm++) acc += t1[mm]*glob_w2[mm*4 + t];
    out_glob[t] = tanhf(acc);
  }
}

// ================= finalize: heads + strategies, one thread per node (f32 out) =================
__global__ void finalize_kernel(
    const float* __restrict__ z, const float* __restrict__ head_w2, const float* __restrict__ head_b2,
    const float* __restrict__ strat_w2, const float* __restrict__ strat_b2, float* __restrict__ out){
  int n = blockIdx.x*256 + threadIdx.x;
  if (n >= N_NODES) return;
  const float* zr = z + (size_t)n*160;
  float y[4];
  #pragma unroll
  for (int k = 0; k < 4; k++){
    float acc = head_b2[k];
    #pragma unroll
    for (int m = 0; m < 32; m++) acc += zr[k*32+m]*head_w2[k*32+m];
    y[k] = acc;
  }
  out[n]             = tanhf(y[0]);
  out[N_NODES + n]   = 1.0f/(1.0f + expf(-y[1]));
  out[2*N_NODES + n] = 1.0f/(1.0f + expf(-y[2]));
  out[3*N_NODES + n] = 1.0f/(1.0f + expf(-y[3]));
  float sv[5], mx = -3.4e38f;
  #pragma unroll
  for (int j = 0; j < 5; j++){
    float acc = strat_b2[j];
    #pragma unroll
    for (int m = 0; m < 32; m++) acc += zr[128+m]*strat_w2[m*5+j];
    sv[j] = acc; mx = fmaxf(mx, acc);
  }
  float se = 0;
  #pragma unroll
  for (int j = 0; j < 5; j++){ sv[j] = expf(sv[j]-mx); se += sv[j]; }
  float inv = 1.0f/se;
  #pragma unroll
  for (int j = 0; j < 5; j++) out[4*N_NODES + (size_t)n*5 + j] = sv[j]*inv;
}

// ======================================================================
extern "C" void kernel_launch(void* const* d_in, const int* in_sizes, int n_in,
                              void* d_out, int out_size, void* d_ws, size_t ws_size,
                              hipStream_t stream){
  float* out = (float*)d_out;   // reference output dtype is float32

  static const int exp_sizes[30] = {
    750000, 1200000, 6000000, 8, 1920, 128, 49152, 384, 384, 3840, 384,
    384, 384, 384, 3136, 8, 8, 8, 16384, 128, 128, 4, 4096, 32, 160, 5,
    256, 32, 128, 4 };
  int host_code = 0;
  if (n_in != 30){
    int nn = n_in < 0 ? 0 : (n_in > 63 ? 63 : n_in);
    host_code = 4096 + 32*nn;
  } else {
    for (int i = 0; i < 30; i++)
      if (in_sizes[i] != exp_sizes[i]){ host_code = 1024 + 8*i; break; }
  }
  if (!host_code && out_size != 9*N_NODES + 4) host_code = 12288;
  if (host_code){
    sentinel_kernel<<<1, 64, 0, stream>>>(host_code, nullptr, nullptr, out);
    return;
  }

  const int* ei = (const int*)d_in[1];

  char* wsp = (char*)d_ws;
  size_t off = 0;
  auto alloc = [&](size_t bytes)->char*{ char* p = wsp + off; off += (bytes + 255) & ~(size_t)255; return p; };

  float* h      = (float*)alloc((size_t)N_NODES*128*4);   // 25.6 MB
  float* hp     = (float*)alloc((size_t)N_NODES*128*4);   // 25.6 MB
  float* a_s    = (float*)alloc((size_t)N_NODES*4*4);
  float* a_d    = (float*)alloc((size_t)N_NODES*4*4);
  float* ae     = (float*)alloc((size_t)N_EDGES*4*4);     // 9.6 MB
  float* attn   = (float*)alloc((size_t)TOT_E*4*4);       // 10.4 MB
  // z[N][160] = 32 MB aliases hp(25.6)+a_s+a_d+head of ae — all dead before heads GEMM
  float* zbuf   = hp;
  int*   srcs   = (int*)alloc((size_t)TOT_E*4);
  int*   eid    = (int*)alloc((size_t)TOT_E*4);
  int*   rowptr = (int*)alloc((size_t)(N_NODES+1)*4);

  const int SN = 27;
  static const int sn_sizes[SN] = {
    8, 1920, 128, 49152, 384, 384, 3840, 384, 384, 384, 384,
    3136, 8, 8, 8, 16384, 128, 128, 4, 4096, 32, 160, 5, 256, 32, 128, 4 };
  static const int sn_input[SN] = {
    3, 4, 5, 6, 7, 8, 9, 10, 11, 12, 13, 14, 15, 16, 17,
    18, 19, 20, 21, 22, 23, 24, 25, 26, 27, 28, 29 };
  float* sarr[SN];
  for (int i = 0; i < SN; i++) sarr[i] = (float*)alloc((size_t)sn_sizes[i]*4);
  float* u_c       = sarr[0];
  float* enc_w_c   = sarr[1];
  float* enc_b_c   = sarr[2];
  float* Wl        = sarr[3];
  float* att_src_c = sarr[4];
  float* att_dst_c = sarr[5];
  float* lin_e_c   = sarr[6];
  float* att_e_c   = sarr[7];
  float* bias_c    = sarr[8];
  float* ln_g_c    = sarr[9];
  float* ln_b_c    = sarr[10];
  float* pool_w_c  = sarr[11];
  float* pool_b_c  = sarr[12];
  float* pln_g_c   = sarr[13];
  float* pln_b_c   = sarr[14];
  float* head_w1_c = sarr[15];
  float* head_b1_c = sarr[16];
  float* head_w2_c = sarr[17];
  float* head_b2_c = sarr[18];
  float* strat_w1_c= sarr[19];
  float* strat_b1_c= sarr[20];
  float* strat_w2_c= sarr[21];
  float* strat_b2_c= sarr[22];
  float* glob_w1_c = sarr[23];
  float* glob_b1_c = sarr[24];
  float* glob_w2_c = sarr[25];
  float* glob_b2_c = sarr[26];

  float* W1cat  = (float*)alloc((size_t)128*160*4);
  float* b1cat  = (float*)alloc(160*4);
  float* Mmat   = (float*)alloc(3*40*4);
  int*   mode   = (int*)alloc(256);
  float* psum   = (float*)alloc((size_t)PB*128*4);
  float* pmax   = (float*)alloc((size_t)PB*128*4);
  size_t zero_begin = off;
  int*   devflags = (int*)alloc(256);
  int*   cnt      = (int*)alloc((size_t)N_NODES*4);
  int*   fill     = (int*)alloc((size_t)N_NODES*4);
  size_t zero_bytes = off - zero_begin;

  if (ws_size < off){
    sentinel_kernel<<<1, 64, 0, stream>>>(8192, nullptr, nullptr, out);
    return;
  }

  hipMemsetAsync(wsp + zero_begin, 0, zero_bytes, stream);

  detect_kernel<<<1, 256, 0, stream>>>(d_in[4], mode);
  check_ei_kernel<<<(2*N_EDGES + 255)/256, 256, 0, stream>>>(ei, devflags);

  CvtTab tab;
  for (int i = 0; i < SN; i++){ tab.s[i] = d_in[sn_input[i]]; tab.d[i] = sarr[i]; tab.n[i] = sn_sizes[i]; }
  cvt_small_kernel<<<SN, 256, 0, stream>>>(tab, mode);

  pack_kernel<<<(128*160 + 255)/256, 256, 0, stream>>>(head_w1_c, strat_w1_c, head_b1_c, strat_b1_c, W1cat, b1cat);
  mmat_kernel<<<1, 128, 0, stream>>>(lin_e_c, att_e_c, Mmat);
  count_kernel<<<(N_EDGES + 255)/256, 256, 0, stream>>>(ei, cnt);
  rowptr_kernel<<<1, 1024, 0, stream>>>(cnt, rowptr);
  scatter_kernel<<<(TOT_E + 255)/256, 256, 0, stream>>>(ei, rowptr, fill, srcs, eid);
  encoder_kernel<<<N_NODES, 128, 0, stream>>>(d_in[0], mode, enc_w_c, enc_b_c, h);

  const int gx = (N_NODES + 127)/128;   // 391
  for (int l = 0; l < NLAYER; l++){
    ae_kernel<<<(N_EDGES + 255)/256, 256, 0, stream>>>(d_in[2], mode, Mmat + l*40, ae);
    gemm_kernel<<<dim3(gx, 1), 256, 0, stream>>>(h, Wl + (size_t)l*128*128, hp, N_NODES, 128, 0, nullptr);
    asad_kernel<<<(N_NODES*4 + 255)/256, 256, 0, stream>>>(hp, att_src_c + l*128, att_dst_c + l*128, a_s, a_d);
    attn_kernel<<<(N_NODES*4 + 255)/256, 256, 0, stream>>>(a_s, a_d, ae, srcs, eid, rowptr, attn);
    aggregate_kernel<<<N_NODES/4, 256, 0, stream>>>(hp, attn, srcs, rowptr,
                                                    bias_c + l*128, ln_g_c + l*128, ln_b_c + l*128, h);
  }

  pool_part_kernel<<<PB, 128, 0, stream>>>(h, psum, pmax);
  global_kernel<<<1, 128, 0, stream>>>(psum, pmax, u_c, pool_w_c, pool_b_c, pln_g_c, pln_b_c,
                                       glob_w1_c, glob_b1_c, glob_w2_c, glob_b2_c, out + 9*N_NODES);
  gemm_kernel<<<dim3(gx, 2), 256, 0, stream>>>(h, W1cat, zbuf, N_NODES, 160, 1, b1cat);
  finalize_kernel<<<(N_NODES + 255)/256, 256, 0, stream>>>(zbuf, head_w2_c, head_b2_c, strat_w2_c, strat_b2_c, out);
  sentinel_kernel<<<1, 64, 0, stream>>>(0, devflags, mode, out);
}

// Round 6
// 673.271 us; speedup vs baseline: 1.9380x; 1.4164x over previous
//
#include <hip/hip_runtime.h>
#include <hip/hip_bf16.h>
#include <hip/hip_fp16.h>

#define N_NODES 50000
#define N_EDGES 600000
#define TOT_E   (N_EDGES + N_NODES)   // 650000 with self loops
#define NLAYER  3
#define PB      200                   // pool partial blocks
#define SCB     512                   // scan block
#define NSB     ((N_NODES + SCB - 1)/SCB)   // 98

typedef __hip_bfloat16 bf16;
__device__ __forceinline__ float b2f(bf16 v){ return __bfloat162float(v); }

// dual-mode load: m=1 -> f32, m=0 -> bf16
__device__ __forceinline__ float ldm(const void* p, long i, int m){
  return m ? ((const float*)p)[i] : b2f(((const bf16*)p)[i]);
}

// ================= input dtype detection =================
__global__ void detect_kernel(const void* probe, int* mode){
  __shared__ float red[256];
  int t = threadIdx.x;
  const bf16* p = (const bf16*)probe;
  float mx = 0.f;
  for (int i = t; i < 1920; i += 256){
    float v = fabsf(b2f(p[i]));
    if (!isfinite(v)) v = 1e30f;
    mx = fmaxf(mx, v);
  }
  red[t] = mx; __syncthreads();
  if (t == 0){
    float m = 0.f;
    for (int i = 0; i < 256; i++) m = fmaxf(m, red[i]);
    mode[0] = (m > 1000.0f) ? 1 : 0;
  }
}

// ================= sentinel (f32 output) =================
__global__ void sentinel_kernel(int host_code, const int* devflags, const int* mode, float* out){
  if (threadIdx.x == 0 && blockIdx.x == 0){
    int code = host_code;
    if (!code && devflags){
      if (devflags[1] > 900)      code = 16384;
      else if (devflags[0])       code = 20480;
    }
    if (code){
      if (mode) code += 512*mode[0];
      out[0] = (float)code;
    }
  }
}

// ================= small weight conversion =================
struct CvtTab { const void* s[27]; float* d[27]; int n[27]; };
__global__ void cvt_small_kernel(CvtTab tab, const int* mode){
  int b = blockIdx.x;
  int m = mode[0];
  const void* s = tab.s[b]; float* d = tab.d[b]; int n = tab.n[b];
  for (int i = threadIdx.x; i < n; i += 256) d[i] = ldm(s, i, m);
}

// ================= count + edge sanity (fused) =================
__global__ void count_kernel(const int* __restrict__ ei, int* __restrict__ cnt, int* devflags){
  int e = blockIdx.x*256 + threadIdx.x;
  if (e >= N_EDGES) return;
  int s = ei[e], d = ei[N_EDGES + e];
  if (((unsigned)s >= N_NODES) || ((unsigned)d >= N_NODES)) atomicOr(&devflags[0], 1);
  else atomicAdd(&cnt[d], 1);
  if (e < 1024 && ei[2*e + 1] == 0) atomicAdd(&devflags[1], 1);
}

// ================= hierarchical exclusive scan of (cnt[i]+1) =================
__global__ __launch_bounds__(SCB) void scan1_kernel(const int* __restrict__ cnt, int* __restrict__ bsum){
  __shared__ int ws[SCB/64];
  int i = blockIdx.x*SCB + threadIdx.x;
  int v = (i < N_NODES) ? cnt[i] + 1 : 0;
  int lane = threadIdx.x & 63, w = threadIdx.x >> 6;
  #pragma unroll
  for (int off = 1; off < 64; off <<= 1) v += __shfl_xor(v, off);
  if (lane == 0) ws[w] = v;
  __syncthreads();
  if (threadIdx.x == 0){
    int s = 0;
    #pragma unroll
    for (int k = 0; k < SCB/64; k++) s += ws[k];
    bsum[blockIdx.x] = s;
  }
}

__global__ void scan2_kernel(int* __restrict__ bsum, int* __restrict__ rowptr){
  if (threadIdx.x == 0 && blockIdx.x == 0){
    int run = 0;
    for (int b = 0; b < NSB; b++){ int t = bsum[b]; bsum[b] = run; run += t; }
    rowptr[N_NODES] = run;
  }
}

__global__ __launch_bounds__(SCB) void scan3_kernel(const int* __restrict__ cnt, const int* __restrict__ bsum,
                                                    int* __restrict__ rowptr){
  __shared__ int sm[SCB];
  int t = threadIdx.x;
  int i = blockIdx.x*SCB + t;
  int v = (i < N_NODES) ? cnt[i] + 1 : 0;
  sm[t] = v; __syncthreads();
  for (int off = 1; off < SCB; off <<= 1){
    int add = (t >= off) ? sm[t-off] : 0;
    __syncthreads();
    sm[t] += add;
    __syncthreads();
  }
  if (i < N_NODES) rowptr[i] = bsum[blockIdx.x] + sm[t] - v;   // exclusive
}

__global__ void scatter_kernel(const int* __restrict__ ei, const int* __restrict__ rowptr,
                               int* __restrict__ fill, int* __restrict__ srcs, int* __restrict__ eid){
  int e = blockIdx.x*256 + threadIdx.x;
  if (e >= TOT_E) return;
  if (e < N_EDGES){
    int s = ei[e], d = ei[N_EDGES + e];
    int pos = rowptr[d] + atomicAdd(&fill[d], 1);
    srcs[pos] = s; eid[pos] = e;
  } else {
    int i = e - N_EDGES;
    int pos = rowptr[i+1] - 1;                 // last slot = self loop
    srcs[pos] = i; eid[pos] = e;
  }
}

// ================= weight packing =================
__global__ void pack_kernel(const float* __restrict__ head_w1, const float* __restrict__ strat_w1,
                            const float* __restrict__ head_b1, const float* __restrict__ strat_b1,
                            float* __restrict__ W1cat, float* __restrict__ b1cat){
  int t = blockIdx.x*256 + threadIdx.x;
  if (t < 128*160){
    int f = t / 160, c = t % 160;
    W1cat[t] = (c < 128) ? head_w1[(c>>5)*4096 + f*32 + (c&31)]
                         : strat_w1[f*32 + (c-128)];
  }
  if (t < 160) b1cat[t] = (t < 128) ? head_b1[t] : strat_b1[t-128];
}

// M[l][k][h] = sum_d We[l][k][h*32+d] * att_edge[l][h][d]
__global__ void mmat_kernel(const float* __restrict__ We, const float* __restrict__ att_edge,
                            float* __restrict__ M){
  int t = threadIdx.x;
  if (t >= 120) return;
  int l = t / 40, r = t % 40, k = r / 4, hh = r % 4;
  float s = 0;
  #pragma unroll
  for (int d = 0; d < 32; d++)
    s += We[l*1280 + k*128 + hh*32 + d] * att_edge[l*128 + hh*32 + d];
  M[t] = s;
}

// ================= encoder (dual-mode x) =================
__global__ __launch_bounds__(128) void encoder_kernel(const void* __restrict__ x_raw, const int* __restrict__ mode,
                                                      const float* __restrict__ enc_w, const float* __restrict__ enc_b,
                                                      float* __restrict__ h){
  __shared__ float xs[16];
  int n = blockIdx.x, j = threadIdx.x;
  if (j < 15) xs[j] = ldm(x_raw, (long)n*15 + j, mode[0]);
  __syncthreads();
  float acc = enc_b[j];
  #pragma unroll
  for (int k = 0; k < 15; k++) acc += xs[k] * enc_w[k*128 + j];
  h[(size_t)n*128 + j] = fmaxf(acc, 0.0f);
}

// ================= per-edge a_e for ALL layers: ae3[e][l*4+h] =================
__global__ void ae_kernel(const void* __restrict__ ea_raw, const int* __restrict__ mode,
                          const float* __restrict__ Mmat, float* __restrict__ ae3){
  int e = blockIdx.x*256 + threadIdx.x;
  if (e >= N_EDGES) return;
  int m = mode[0];
  float v[10];
  #pragma unroll
  for (int k = 0; k < 10; k++) v[k] = ldm(ea_raw, (long)e*10 + k, m);
  #pragma unroll
  for (int l = 0; l < 3; l++)
    #pragma unroll
    for (int hh = 0; hh < 4; hh++){
      float s = 0;
      #pragma unroll
      for (int k = 0; k < 10; k++) s += v[k]*Mmat[l*40 + k*4 + hh];
      ae3[(size_t)e*12 + l*4 + hh] = s;
    }
}

// ================= SGEMM: mode 0 -> hp fp16 + a_s/a_d epilogue; mode 1 -> f32 bias+relu =================
#define BK 16
__global__ __launch_bounds__(256) void gemm_kernel(
    const float* __restrict__ A, const float* __restrict__ B, float* __restrict__ Cf,
    __half* __restrict__ Ch, int M, int ldb, int mode, const float* __restrict__ bias,
    const float* __restrict__ att_src, const float* __restrict__ att_dst,
    float* __restrict__ a_s, float* __restrict__ a_d){
  __shared__ float As[BK][128+4];
  __shared__ float Bs[BK][128];
  int t = threadIdx.x;
  int tx = t & 15, ty = t >> 4;
  int n0 = blockIdx.x * 128;
  int j0 = blockIdx.y * 128;
  float acc[8][8];
  #pragma unroll
  for (int i = 0; i < 8; i++)
    #pragma unroll
    for (int j = 0; j < 8; j++) acc[i][j] = 0.0f;

  for (int kb = 0; kb < 128; kb += BK){
    #pragma unroll
    for (int q = 0; q < 2; q++){
      int v = t*2 + q;
      int row = v >> 2, c4 = v & 3;
      int gn = n0 + row;
      float4 f = make_float4(0,0,0,0);
      if (gn < M) f = *(const float4*)(A + (size_t)gn*128 + kb + c4*4);
      As[c4*4+0][row] = f.x; As[c4*4+1][row] = f.y;
      As[c4*4+2][row] = f.z; As[c4*4+3][row] = f.w;
    }
    #pragma unroll
    for (int q = 0; q < 2; q++){
      int v = t*2 + q;
      int kk = v >> 5, j4 = v & 31;
      int gj = j0 + j4*4;
      float4 f = make_float4(0,0,0,0);
      if (gj < ldb) f = *(const float4*)(B + (size_t)(kb+kk)*ldb + gj);
      *(float4*)&Bs[kk][j4*4] = f;
    }
    __syncthreads();
    #pragma unroll
    for (int kk = 0; kk < BK; kk++){
      float4 a0 = *(const float4*)&As[kk][ty*8];
      float4 a1 = *(const float4*)&As[kk][ty*8+4];
      float4 b0 = *(const float4*)&Bs[kk][tx*8];
      float4 b1 = *(const float4*)&Bs[kk][tx*8+4];
      float av[8] = {a0.x,a0.y,a0.z,a0.w,a1.x,a1.y,a1.z,a1.w};
      float bv[8] = {b0.x,b0.y,b0.z,b0.w,b1.x,b1.y,b1.z,b1.w};
      #pragma unroll
      for (int i = 0; i < 8; i++)
        #pragma unroll
        for (int j = 0; j < 8; j++) acc[i][j] += av[i]*bv[j];
    }
    __syncthreads();
  }

  if (mode == 0){
    // cols tx*8..tx*8+7, head = tx>>2, dims within head dd = (tx&3)*8 + jj
    int head = tx >> 2;
    float as_w[8], ad_w[8];
    #pragma unroll
    for (int jj = 0; jj < 8; jj++){
      int dd = (tx&3)*8 + jj;
      as_w[jj] = att_src[head*32 + dd];
      ad_w[jj] = att_dst[head*32 + dd];
    }
    #pragma unroll
    for (int i = 0; i < 8; i++){
      int gn = n0 + ty*8 + i;
      float ps = 0, pd = 0;
      #pragma unroll
      for (int jj = 0; jj < 8; jj++){ ps += acc[i][jj]*as_w[jj]; pd += acc[i][jj]*ad_w[jj]; }
      ps += __shfl_xor(ps, 1); ps += __shfl_xor(ps, 2);
      pd += __shfl_xor(pd, 1); pd += __shfl_xor(pd, 2);
      if (((tx & 3) == 0) && gn < M){ a_s[gn*4 + head] = ps; a_d[gn*4 + head] = pd; }
      if (gn < M){
        union { __half2 h2[4]; float4 f4; } u;
        #pragma unroll
        for (int q = 0; q < 4; q++){
          __half2 hh;
          hh.x = __float2half(acc[i][2*q]);
          hh.y = __float2half(acc[i][2*q+1]);
          u.h2[q] = hh;
        }
        *(float4*)(Ch + (size_t)gn*128 + tx*8) = u.f4;
      }
    }
  } else {
    int jb = j0 + tx*8;
    bool jok = jb < ldb;
    float bi[8];
    if (jok){
      #pragma unroll
      for (int jj = 0; jj < 8; jj++) bi[jj] = bias[jb+jj];
    }
    #pragma unroll
    for (int i = 0; i < 8; i++){
      int gn = n0 + ty*8 + i;
      if (gn < M && jok){
        float o[8];
        #pragma unroll
        for (int jj = 0; jj < 8; jj++) o[jj] = fmaxf(acc[i][jj] + bi[jj], 0.0f);
        *(float4*)(Cf + (size_t)gn*ldb + jb)     = make_float4(o[0],o[1],o[2],o[3]);
        *(float4*)(Cf + (size_t)gn*ldb + jb + 4) = make_float4(o[4],o[5],o[6],o[7]);
      }
    }
  }
}

// ================= fused attention softmax + aggregate + residual + LN: one wave per node =================
__global__ __launch_bounds__(256) void fused_agg_kernel(
    const __half* __restrict__ hp, const float* __restrict__ a_s, const float* __restrict__ a_d,
    const float* __restrict__ ae3, int l, const int* __restrict__ srcs, const int* __restrict__ eid,
    const int* __restrict__ rowptr, const float* __restrict__ bias_l,
    const float* __restrict__ ln_g_l, const float* __restrict__ ln_b_l, float* __restrict__ h){
  int n = blockIdx.x*4 + (threadIdx.x >> 6);
  int lane = threadIdx.x & 63;
  int p0 = rowptr[n], p1 = rowptr[n+1];
  int deg = p1 - p0 - 1;                       // real incoming edges
  int hh = lane & 3;                           // head for alpha computation
  int esl = lane >> 2;                         // edge slot 0..15
  float adv = a_d[n*4 + hh];
  float asn = a_s[n*4 + hh];

  // phase 1: online softmax over real edges (per head class hh)
  float m = -3.4e38f, ls = 0.f, ssum = 0.f;
  for (int base = p0; base < p1-1; base += 16){
    int p = base + esl;
    if (p < p1-1){
      float aev = ae3[(size_t)eid[p]*12 + l*4 + hh];
      float al = a_s[srcs[p]*4 + hh] + adv + aev;
      al = (al > 0.f) ? al : 0.2f*al;          // leaky_relu 0.2
      ssum += aev;
      if (al > m){ ls = ls*__expf(m - al) + 1.f; m = al; }
      else ls += __expf(al - m);
    }
  }
  // butterfly over the 16 lanes sharing hh (xor offsets 4..32 preserve lane&3)
  #pragma unroll
  for (int off = 4; off <= 32; off <<= 1){
    float mo = __shfl_xor(m, off);
    float lo = __shfl_xor(ls, off);
    float so = __shfl_xor(ssum, off);
    ssum += so;
    float mn = fmaxf(m, mo);
    ls = ls*__expf(m - mn) + lo*__expf(mo - mn);
    m = mn;
  }
  // self loop: a_e = mean of real-edge a_e (mean commutes with linear map)
  float aself = ssum / (float)(deg > 0 ? deg : 1);
  float als = asn + adv + aself;
  als = (als > 0.f) ? als : 0.2f*als;
  float mx = fmaxf(m, als);
  float denom = ls*__expf(m - mx) + __expf(als - mx);

  int hsel = lane >> 4;                        // head for this lane's output cols
  float mxh  = __shfl(mx, hsel);
  float invd = 1.f/__shfl(denom, hsel);
  float alsh = __shfl(als, hsel);

  // phase 2: weighted aggregation (recompute alphas lane-parallel, broadcast via shfl)
  float acc0 = 0.f, acc1 = 0.f;
  for (int base = p0; base < p1-1; base += 16){
    int p = base + esl;
    float alpha = 0.f; int sv = 0;
    if (p < p1-1){
      float aev = ae3[(size_t)eid[p]*12 + l*4 + hh];
      sv = srcs[p];
      float al = a_s[sv*4 + hh] + adv + aev;
      alpha = (al > 0.f) ? al : 0.2f*al;
    }
    int cnt_e = min(16, p1-1-base);
    for (int j = 0; j < cnt_e; j++){
      float aj = __shfl(alpha, j*4 + hsel);
      int   sj = __shfl(sv,    j*4);
      float w = __expf(aj - mxh)*invd;
      __half2 hv = *((const __half2*)(hp + (size_t)sj*128) + lane);
      acc0 += w*__half2float(hv.x);
      acc1 += w*__half2float(hv.y);
    }
  }
  {  // self contribution
    float w = __expf(alsh - mxh)*invd;
    __half2 hv = *((const __half2*)(hp + (size_t)n*128) + lane);
    acc0 += w*__half2float(hv.x);
    acc1 += w*__half2float(hv.y);
  }
  // bias + residual + LayerNorm (wave-wide)
  float2 res = *(const float2*)(h + (size_t)n*128 + lane*2);
  float2 bi  = *(const float2*)(bias_l + lane*2);
  float v0 = acc0 + bi.x + res.x;
  float v1 = acc1 + bi.y + res.y;
  float s = v0 + v1, sq = v0*v0 + v1*v1;
  #pragma unroll
  for (int off = 32; off >= 1; off >>= 1){ s += __shfl_xor(s, off); sq += __shfl_xor(sq, off); }
  float mu  = s * (1.0f/128.0f);
  float var = sq * (1.0f/128.0f) - mu*mu;
  float rs  = rsqrtf(fmaxf(var, 0.0f) + 1e-5f);
  float2 g  = *(const float2*)(ln_g_l + lane*2);
  float2 bb = *(const float2*)(ln_b_l + lane*2);
  float2 o;
  o.x = (v0 - mu)*rs*g.x + bb.x;
  o.y = (v1 - mu)*rs*g.y + bb.y;
  *(float2*)(h + (size_t)n*128 + lane*2) = o;
}

// ================= pooling partials (deterministic) =================
__global__ __launch_bounds__(128) void pool_part_kernel(const float* __restrict__ h,
                                                        float* __restrict__ psum, float* __restrict__ pmax){
  int b = blockIdx.x, j = threadIdx.x;
  int nb = b*(N_NODES/PB), ne = nb + (N_NODES/PB);
  float s = 0, m = -3.4e38f;
  for (int n = nb; n < ne; n++){ float v = h[(size_t)n*128 + j]; s += v; m = fmaxf(m, v); }
  psum[b*128 + j] = s; pmax[b*128 + j] = m;
}

// ================= pooled MLP + global head (f32 out) =================
__global__ __launch_bounds__(128) void global_kernel(
    const float* __restrict__ psum, const float* __restrict__ pmax,
    const float* __restrict__ u, const float* __restrict__ pool_w, const float* __restrict__ pool_b,
    const float* __restrict__ pool_ln_g, const float* __restrict__ pool_ln_b,
    const float* __restrict__ glob_w1, const float* __restrict__ glob_b1,
    const float* __restrict__ glob_w2, const float* __restrict__ glob_b2, float* __restrict__ out_glob){
  __shared__ float pooled[392];
  __shared__ float gv[8];
  __shared__ float t1[32];
  __shared__ float mv[2];
  int t = threadIdx.x;
  float s = 0, m = -3.4e38f;
  for (int b = 0; b < PB; b++){ s += psum[b*128 + t]; m = fmaxf(m, pmax[b*128 + t]); }
  pooled[t]       = s * (1.0f/(float)N_NODES);
  pooled[128 + t] = m;
  pooled[256 + t] = s;
  if (t < 8) pooled[384 + t] = u[t];
  __syncthreads();
  if (t < 8){
    float acc = pool_b[t];
    for (int f = 0; f < 392; f++) acc += pooled[f]*pool_w[f*8 + t];
    gv[t] = fmaxf(acc, 0.0f);
  }
  __syncthreads();
  if (t == 0){
    float mu = 0; for (int i = 0; i < 8; i++) mu += gv[i];
    mu *= 0.125f;
    float var = 0; for (int i = 0; i < 8; i++){ float d = gv[i]-mu; var += d*d; }
    var *= 0.125f;
    mv[0] = mu; mv[1] = rsqrtf(var + 1e-5f);
  }
  __syncthreads();
  float gnorm = (t < 8) ? (gv[t]-mv[0])*mv[1]*pool_ln_g[t] + pool_ln_b[t] : 0.0f;
  __syncthreads();
  if (t < 8) gv[t] = gnorm;
  __syncthreads();
  if (t < 32){
    float acc = glob_b1[t];
    for (int q = 0; q < 8; q++) acc += gv[q]*glob_w1[q*32 + t];
    t1[t] = fmaxf(acc, 0.0f);
  }
  __syncthreads();
  if (t < 4){
    float acc = glob_b2[t];
    for (int mm = 0; mm < 32; mm++) acc += t1[mm]*glob_w2[mm*4 + t];
    out_glob[t] = tanhf(acc);
  }
}

// ================= finalize: heads + strategies (f32 out) =================
__global__ void finalize_kernel(
    const float* __restrict__ z, const float* __restrict__ head_w2, const float* __restrict__ head_b2,
    const float* __restrict__ strat_w2, const float* __restrict__ strat_b2, float* __restrict__ out){
  int n = blockIdx.x*256 + threadIdx.x;
  if (n >= N_NODES) return;
  const float* zr = z + (size_t)n*160;
  float y[4];
  #pragma unroll
  for (int k = 0; k < 4; k++){
    float acc = head_b2[k];
    #pragma unroll
    for (int m = 0; m < 32; m++) acc += zr[k*32+m]*head_w2[k*32+m];
    y[k] = acc;
  }
  out[n]             = tanhf(y[0]);
  out[N_NODES + n]   = 1.0f/(1.0f + expf(-y[1]));
  out[2*N_NODES + n] = 1.0f/(1.0f + expf(-y[2]));
  out[3*N_NODES + n] = 1.0f/(1.0f + expf(-y[3]));
  float sv[5], mx = -3.4e38f;
  #pragma unroll
  for (int j = 0; j < 5; j++){
    float acc = strat_b2[j];
    #pragma unroll
    for (int m = 0; m < 32; m++) acc += zr[128+m]*strat_w2[m*5+j];
    sv[j] = acc; mx = fmaxf(mx, acc);
  }
  float se = 0;
  #pragma unroll
  for (int j = 0; j < 5; j++){ sv[j] = expf(sv[j]-mx); se += sv[j]; }
  float inv = 1.0f/se;
  #pragma unroll
  for (int j = 0; j < 5; j++) out[4*N_NODES + (size_t)n*5 + j] = sv[j]*inv;
}

// ======================================================================
extern "C" void kernel_launch(void* const* d_in, const int* in_sizes, int n_in,
                              void* d_out, int out_size, void* d_ws, size_t ws_size,
                              hipStream_t stream){
  float* out = (float*)d_out;

  static const int exp_sizes[30] = {
    750000, 1200000, 6000000, 8, 1920, 128, 49152, 384, 384, 3840, 384,
    384, 384, 384, 3136, 8, 8, 8, 16384, 128, 128, 4, 4096, 32, 160, 5,
    256, 32, 128, 4 };
  int host_code = 0;
  if (n_in != 30){
    int nn = n_in < 0 ? 0 : (n_in > 63 ? 63 : n_in);
    host_code = 4096 + 32*nn;
  } else {
    for (int i = 0; i < 30; i++)
      if (in_sizes[i] != exp_sizes[i]){ host_code = 1024 + 8*i; break; }
  }
  if (!host_code && out_size != 9*N_NODES + 4) host_code = 12288;
  if (host_code){
    sentinel_kernel<<<1, 64, 0, stream>>>(host_code, nullptr, nullptr, out);
    return;
  }

  const int* ei = (const int*)d_in[1];

  char* wsp = (char*)d_ws;
  size_t off = 0;
  auto alloc = [&](size_t bytes)->char*{ char* p = wsp + off; off += (bytes + 255) & ~(size_t)255; return p; };

  float*  h    = (float*)alloc((size_t)N_NODES*128*4);    // 25.6 MB
  __half* hp   = (__half*)alloc((size_t)N_NODES*128*2);   // 12.8 MB
  float*  a_s  = (float*)alloc((size_t)N_NODES*4*4);      // 0.8 MB
  float*  a_d  = (float*)alloc((size_t)N_NODES*4*4);      // 0.8 MB
  float*  ae3  = (float*)alloc((size_t)N_EDGES*12*4);     // 28.8 MB
  // z[N][160] f32 = 32 MB aliases hp+a_s+a_d+ae3 (43.2 MB span) — all dead before heads GEMM
  float*  zbuf = (float*)hp;
  int*   srcs   = (int*)alloc((size_t)TOT_E*4);
  int*   eid    = (int*)alloc((size_t)TOT_E*4);
  int*   rowptr = (int*)alloc((size_t)(N_NODES+1)*4);
  int*   bsum   = (int*)alloc((size_t)NSB*4);

  const int SN = 27;
  static const int sn_sizes[SN] = {
    8, 1920, 128, 49152, 384, 384, 3840, 384, 384, 384, 384,
    3136, 8, 8, 8, 16384, 128, 128, 4, 4096, 32, 160, 5, 256, 32, 128, 4 };
  static const int sn_input[SN] = {
    3, 4, 5, 6, 7, 8, 9, 10, 11, 12, 13, 14, 15, 16, 17,
    18, 19, 20, 21, 22, 23, 24, 25, 26, 27, 28, 29 };
  float* sarr[SN];
  for (int i = 0; i < SN; i++) sarr[i] = (float*)alloc((size_t)sn_sizes[i]*4);
  float* u_c       = sarr[0];
  float* enc_w_c   = sarr[1];
  float* enc_b_c   = sarr[2];
  float* Wl        = sarr[3];
  float* att_src_c = sarr[4];
  float* att_dst_c = sarr[5];
  float* lin_e_c   = sarr[6];
  float* att_e_c   = sarr[7];
  float* bias_c    = sarr[8];
  float* ln_g_c    = sarr[9];
  float* ln_b_c    = sarr[10];
  float* pool_w_c  = sarr[11];
  float* pool_b_c  = sarr[12];
  float* pln_g_c   = sarr[13];
  float* pln_b_c   = sarr[14];
  float* head_w1_c = sarr[15];
  float* head_b1_c = sarr[16];
  float* head_w2_c = sarr[17];
  float* head_b2_c = sarr[18];
  float* strat_w1_c= sarr[19];
  float* strat_b1_c= sarr[20];
  float* strat_w2_c= sarr[21];
  float* strat_b2_c= sarr[22];
  float* glob_w1_c = sarr[23];
  float* glob_b1_c = sarr[24];
  float* glob_w2_c = sarr[25];
  float* glob_b2_c = sarr[26];

  float* W1cat  = (float*)alloc((size_t)128*160*4);
  float* b1cat  = (float*)alloc(160*4);
  float* Mmat   = (float*)alloc(3*40*4);
  int*   mode   = (int*)alloc(256);
  float* psum   = (float*)alloc((size_t)PB*128*4);
  float* pmax   = (float*)alloc((size_t)PB*128*4);
  size_t zero_begin = off;
  int*   devflags = (int*)alloc(256);
  int*   cnt      = (int*)alloc((size_t)N_NODES*4);
  int*   fill     = (int*)alloc((size_t)N_NODES*4);
  size_t zero_bytes = off - zero_begin;

  if (ws_size < off){
    sentinel_kernel<<<1, 64, 0, stream>>>(8192, nullptr, nullptr, out);
    return;
  }

  hipMemsetAsync(wsp + zero_begin, 0, zero_bytes, stream);

  detect_kernel<<<1, 256, 0, stream>>>(d_in[4], mode);

  CvtTab tab;
  for (int i = 0; i < SN; i++){ tab.s[i] = d_in[sn_input[i]]; tab.d[i] = sarr[i]; tab.n[i] = sn_sizes[i]; }
  cvt_small_kernel<<<SN, 256, 0, stream>>>(tab, mode);

  pack_kernel<<<(128*160 + 255)/256, 256, 0, stream>>>(head_w1_c, strat_w1_c, head_b1_c, strat_b1_c, W1cat, b1cat);
  mmat_kernel<<<1, 128, 0, stream>>>(lin_e_c, att_e_c, Mmat);
  count_kernel<<<(N_EDGES + 255)/256, 256, 0, stream>>>(ei, cnt, devflags);
  scan1_kernel<<<NSB, SCB, 0, stream>>>(cnt, bsum);
  scan2_kernel<<<1, 64, 0, stream>>>(bsum, rowptr);
  scan3_kernel<<<NSB, SCB, 0, stream>>>(cnt, bsum, rowptr);
  scatter_kernel<<<(TOT_E + 255)/256, 256, 0, stream>>>(ei, rowptr, fill, srcs, eid);
  encoder_kernel<<<N_NODES, 128, 0, stream>>>(d_in[0], mode, enc_w_c, enc_b_c, h);
  ae_kernel<<<(N_EDGES + 255)/256, 256, 0, stream>>>(d_in[2], mode, Mmat, ae3);

  const int gx = (N_NODES + 127)/128;   // 391
  for (int l = 0; l < NLAYER; l++){
    gemm_kernel<<<dim3(gx, 1), 256, 0, stream>>>(h, Wl + (size_t)l*128*128, nullptr, hp, N_NODES, 128, 0,
                                                 nullptr, att_src_c + l*128, att_dst_c + l*128, a_s, a_d);
    fused_agg_kernel<<<N_NODES/4, 256, 0, stream>>>(hp, a_s, a_d, ae3, l, srcs, eid, rowptr,
                                                    bias_c + l*128, ln_g_c + l*128, ln_b_c + l*128, h);
  }

  pool_part_kernel<<<PB, 128, 0, stream>>>(h, psum, pmax);
  global_kernel<<<1, 128, 0, stream>>>(psum, pmax, u_c, pool_w_c, pool_b_c, pln_g_c, pln_b_c,
                                       glob_w1_c, glob_b1_c, glob_w2_c, glob_b2_c, out + 9*N_NODES);
  gemm_kernel<<<dim3(gx, 2), 256, 0, stream>>>(h, W1cat, zbuf, nullptr, N_NODES, 160, 1, b1cat,
                                               nullptr, nullptr, nullptr, nullptr);
  finalize_kernel<<<(N_NODES + 255)/256, 256, 0, stream>>>(zbuf, head_w2_c, head_b2_c, strat_w2_c, strat_b2_c, out);
  sentinel_kernel<<<1, 64, 0, stream>>>(0, devflags, mode, out);
}

// Round 7
// 554.758 us; speedup vs baseline: 2.3520x; 1.2136x over previous
//
#include <hip/hip_runtime.h>
#include <hip/hip_bf16.h>
#include <hip/hip_fp16.h>

#define N_NODES 50000
#define N_EDGES 600000
#define TOT_E   (N_EDGES + N_NODES)   // 650000 with self loops
#define NLAYER  3
#define PB      200                   // pool partial blocks
#define SCB     512                   // scan block
#define NSB     ((N_NODES + SCB - 1)/SCB)   // 98
#define CAP     96                    // max cached in-degree (fallback if exceeded)

typedef __hip_bfloat16 bf16;
__device__ __forceinline__ float b2f(bf16 v){ return __bfloat162float(v); }

// dual-mode load: m=1 -> f32, m=0 -> bf16
__device__ __forceinline__ float ldm(const void* p, long i, int m){
  return m ? ((const float*)p)[i] : b2f(((const bf16*)p)[i]);
}

// ================= input dtype detection =================
__global__ void detect_kernel(const void* probe, int* mode){
  __shared__ float red[256];
  int t = threadIdx.x;
  const bf16* p = (const bf16*)probe;
  float mx = 0.f;
  for (int i = t; i < 1920; i += 256){
    float v = fabsf(b2f(p[i]));
    if (!isfinite(v)) v = 1e30f;
    mx = fmaxf(mx, v);
  }
  red[t] = mx; __syncthreads();
  if (t == 0){
    float m = 0.f;
    for (int i = 0; i < 256; i++) m = fmaxf(m, red[i]);
    mode[0] = (m > 1000.0f) ? 1 : 0;
  }
}

// ================= sentinel (f32 output) =================
__global__ void sentinel_kernel(int host_code, const int* devflags, const int* mode, float* out){
  if (threadIdx.x == 0 && blockIdx.x == 0){
    int code = host_code;
    if (!code && devflags){
      if (devflags[1] > 900)      code = 16384;
      else if (devflags[0])       code = 20480;
    }
    if (code){
      if (mode) code += 512*mode[0];
      out[0] = (float)code;
    }
  }
}

// ================= small weight conversion (2-D grid for parallelism) =================
struct CvtTab { const void* s[27]; float* d[27]; int n[27]; };
__global__ void cvt_small_kernel(CvtTab tab, const int* mode){
  int b = blockIdx.x;
  int i = blockIdx.y*256 + threadIdx.x;
  if (i < tab.n[b]) tab.d[b][i] = ldm(tab.s[b], i, mode[0]);
}

// ================= count + edge sanity (fused) =================
__global__ void count_kernel(const int* __restrict__ ei, int* __restrict__ cnt, int* devflags){
  int e = blockIdx.x*256 + threadIdx.x;
  if (e >= N_EDGES) return;
  int s = ei[e], d = ei[N_EDGES + e];
  if (((unsigned)s >= N_NODES) || ((unsigned)d >= N_NODES)) atomicOr(&devflags[0], 1);
  else atomicAdd(&cnt[d], 1);
  if (e < 1024 && ei[2*e + 1] == 0) atomicAdd(&devflags[1], 1);
}

// ================= hierarchical exclusive scan of (cnt[i]+1) =================
__global__ __launch_bounds__(SCB) void scan1_kernel(const int* __restrict__ cnt, int* __restrict__ bsum){
  __shared__ int ws[SCB/64];
  int i = blockIdx.x*SCB + threadIdx.x;
  int v = (i < N_NODES) ? cnt[i] + 1 : 0;
  int lane = threadIdx.x & 63, w = threadIdx.x >> 6;
  #pragma unroll
  for (int off = 1; off < 64; off <<= 1) v += __shfl_xor(v, off);
  if (lane == 0) ws[w] = v;
  __syncthreads();
  if (threadIdx.x == 0){
    int s = 0;
    #pragma unroll
    for (int k = 0; k < SCB/64; k++) s += ws[k];
    bsum[blockIdx.x] = s;
  }
}

__global__ void scan2_kernel(int* __restrict__ bsum, int* __restrict__ rowptr){
  if (threadIdx.x == 0 && blockIdx.x == 0){
    int run = 0;
    for (int b = 0; b < NSB; b++){ int t = bsum[b]; bsum[b] = run; run += t; }
    rowptr[N_NODES] = run;
  }
}

__global__ __launch_bounds__(SCB) void scan3_kernel(const int* __restrict__ cnt, const int* __restrict__ bsum,
                                                    int* __restrict__ rowptr){
  __shared__ int sm[SCB];
  int t = threadIdx.x;
  int i = blockIdx.x*SCB + t;
  int v = (i < N_NODES) ? cnt[i] + 1 : 0;
  sm[t] = v; __syncthreads();
  for (int off = 1; off < SCB; off <<= 1){
    int add = (t >= off) ? sm[t-off] : 0;
    __syncthreads();
    sm[t] += add;
    __syncthreads();
  }
  if (i < N_NODES) rowptr[i] = bsum[blockIdx.x] + sm[t] - v;   // exclusive
}

// scatter: srcs in CSR order + inverse map pos_of[e]
__global__ void scatter_kernel(const int* __restrict__ ei, const int* __restrict__ rowptr,
                               int* __restrict__ fill, int* __restrict__ srcs, int* __restrict__ pos_of){
  int e = blockIdx.x*256 + threadIdx.x;
  if (e >= TOT_E) return;
  if (e < N_EDGES){
    int s = ei[e], d = ei[N_EDGES + e];
    int pos = rowptr[d] + atomicAdd(&fill[d], 1);
    srcs[pos] = s; pos_of[e] = pos;
  } else {
    int i = e - N_EDGES;
    srcs[rowptr[i+1] - 1] = i;                 // last slot = self loop
  }
}

// ================= weight packing =================
__global__ void pack_kernel(const float* __restrict__ head_w1, const float* __restrict__ strat_w1,
                            const float* __restrict__ head_b1, const float* __restrict__ strat_b1,
                            float* __restrict__ W1cat, float* __restrict__ b1cat){
  int t = blockIdx.x*256 + threadIdx.x;
  if (t < 128*160){
    int f = t / 160, c = t % 160;
    W1cat[t] = (c < 128) ? head_w1[(c>>5)*4096 + f*32 + (c&31)]
                         : strat_w1[f*32 + (c-128)];
  }
  if (t < 160) b1cat[t] = (t < 128) ? head_b1[t] : strat_b1[t-128];
}

// M[l][k][h] = sum_d We[l][k][h*32+d] * att_edge[l][h][d]
__global__ void mmat_kernel(const float* __restrict__ We, const float* __restrict__ att_edge,
                            float* __restrict__ M){
  int t = threadIdx.x;
  if (t >= 120) return;
  int l = t / 40, r = t % 40, k = r / 4, hh = r % 4;
  float s = 0;
  #pragma unroll
  for (int d = 0; d < 32; d++)
    s += We[l*1280 + k*128 + hh*32 + d] * att_edge[l*128 + hh*32 + d];
  M[t] = s;
}

// ================= encoder (dual-mode x) =================
__global__ __launch_bounds__(128) void encoder_kernel(const void* __restrict__ x_raw, const int* __restrict__ mode,
                                                      const float* __restrict__ enc_w, const float* __restrict__ enc_b,
                                                      float* __restrict__ h){
  __shared__ float xs[16];
  int n = blockIdx.x, j = threadIdx.x;
  if (j < 15) xs[j] = ldm(x_raw, (long)n*15 + j, mode[0]);
  __syncthreads();
  float acc = enc_b[j];
  #pragma unroll
  for (int k = 0; k < 15; k++) acc += xs[k] * enc_w[k*128 + j];
  h[(size_t)n*128 + j] = fmaxf(acc, 0.0f);
}

// ================= per-edge a_e, all layers, written in CSR order =================
// aec layout: float4 array, layer l entry at [l*TOT_E + pos]
__global__ void ae_kernel(const void* __restrict__ ea_raw, const int* __restrict__ mode,
                          const float* __restrict__ Mmat, const int* __restrict__ pos_of,
                          float4* __restrict__ aec){
  int e = blockIdx.x*256 + threadIdx.x;
  if (e >= N_EDGES) return;
  int m = mode[0];
  float v[10];
  #pragma unroll
  for (int k = 0; k < 10; k++) v[k] = ldm(ea_raw, (long)e*10 + k, m);
  int p = pos_of[e];
  #pragma unroll
  for (int l = 0; l < 3; l++){
    float r[4];
    #pragma unroll
    for (int hh = 0; hh < 4; hh++){
      float s = 0;
      #pragma unroll
      for (int k = 0; k < 10; k++) s += v[k]*Mmat[l*40 + k*4 + hh];
      r[hh] = s;
    }
    aec[(size_t)l*TOT_E + p] = make_float4(r[0], r[1], r[2], r[3]);
  }
}

// ================= SGEMM: mode 0 -> hp fp16 + a_s/a_d epilogue; mode 1 -> f32 bias+relu =================
#define BK 16
__global__ __launch_bounds__(256) void gemm_kernel(
    const float* __restrict__ A, const float* __restrict__ B, float* __restrict__ Cf,
    __half* __restrict__ Ch, int M, int ldb, int mode, const float* __restrict__ bias,
    const float* __restrict__ att_src, const float* __restrict__ att_dst,
    float* __restrict__ a_s, float* __restrict__ a_d){
  __shared__ float As[BK][128+4];
  __shared__ float Bs[BK][128];
  int t = threadIdx.x;
  int tx = t & 15, ty = t >> 4;
  int n0 = blockIdx.x * 128;
  int j0 = blockIdx.y * 128;
  float acc[8][8];
  #pragma unroll
  for (int i = 0; i < 8; i++)
    #pragma unroll
    for (int j = 0; j < 8; j++) acc[i][j] = 0.0f;

  for (int kb = 0; kb < 128; kb += BK){
    #pragma unroll
    for (int q = 0; q < 2; q++){
      int v = t*2 + q;
      int row = v >> 2, c4 = v & 3;
      int gn = n0 + row;
      float4 f = make_float4(0,0,0,0);
      if (gn < M) f = *(const float4*)(A + (size_t)gn*128 + kb + c4*4);
      As[c4*4+0][row] = f.x; As[c4*4+1][row] = f.y;
      As[c4*4+2][row] = f.z; As[c4*4+3][row] = f.w;
    }
    #pragma unroll
    for (int q = 0; q < 2; q++){
      int v = t*2 + q;
      int kk = v >> 5, j4 = v & 31;
      int gj = j0 + j4*4;
      float4 f = make_float4(0,0,0,0);
      if (gj < ldb) f = *(const float4*)(B + (size_t)(kb+kk)*ldb + gj);
      *(float4*)&Bs[kk][j4*4] = f;
    }
    __syncthreads();
    #pragma unroll
    for (int kk = 0; kk < BK; kk++){
      float4 a0 = *(const float4*)&As[kk][ty*8];
      float4 a1 = *(const float4*)&As[kk][ty*8+4];
      float4 b0 = *(const float4*)&Bs[kk][tx*8];
      float4 b1 = *(const float4*)&Bs[kk][tx*8+4];
      float av[8] = {a0.x,a0.y,a0.z,a0.w,a1.x,a1.y,a1.z,a1.w};
      float bv[8] = {b0.x,b0.y,b0.z,b0.w,b1.x,b1.y,b1.z,b1.w};
      #pragma unroll
      for (int i = 0; i < 8; i++)
        #pragma unroll
        for (int j = 0; j < 8; j++) acc[i][j] += av[i]*bv[j];
    }
    __syncthreads();
  }

  if (mode == 0){
    int head = tx >> 2;
    float as_w[8], ad_w[8];
    #pragma unroll
    for (int jj = 0; jj < 8; jj++){
      int dd = (tx&3)*8 + jj;
      as_w[jj] = att_src[head*32 + dd];
      ad_w[jj] = att_dst[head*32 + dd];
    }
    #pragma unroll
    for (int i = 0; i < 8; i++){
      int gn = n0 + ty*8 + i;
      float ps = 0, pd = 0;
      #pragma unroll
      for (int jj = 0; jj < 8; jj++){ ps += acc[i][jj]*as_w[jj]; pd += acc[i][jj]*ad_w[jj]; }
      ps += __shfl_xor(ps, 1); ps += __shfl_xor(ps, 2);
      pd += __shfl_xor(pd, 1); pd += __shfl_xor(pd, 2);
      if (((tx & 3) == 0) && gn < M){ a_s[gn*4 + head] = ps; a_d[gn*4 + head] = pd; }
      if (gn < M){
        union { __half2 h2[4]; float4 f4; } u;
        #pragma unroll
        for (int q = 0; q < 4; q++){
          __half2 hh;
          hh.x = __float2half(acc[i][2*q]);
          hh.y = __float2half(acc[i][2*q+1]);
          u.h2[q] = hh;
        }
        *(float4*)(Ch + (size_t)gn*128 + tx*8) = u.f4;
      }
    }
  } else {
    int jb = j0 + tx*8;
    bool jok = jb < ldb;
    float bi[8];
    if (jok){
      #pragma unroll
      for (int jj = 0; jj < 8; jj++) bi[jj] = bias[jb+jj];
    }
    #pragma unroll
    for (int i = 0; i < 8; i++){
      int gn = n0 + ty*8 + i;
      if (gn < M && jok){
        float o[8];
        #pragma unroll
        for (int jj = 0; jj < 8; jj++) o[jj] = fmaxf(acc[i][jj] + bi[jj], 0.0f);
        *(float4*)(Cf + (size_t)gn*ldb + jb)     = make_float4(o[0],o[1],o[2],o[3]);
        *(float4*)(Cf + (size_t)gn*ldb + jb + 4) = make_float4(o[4],o[5],o[6],o[7]);
      }
    }
  }
}

// ================= fused softmax + aggregate + residual + LN: one wave per node =================
// aecl = aec for this layer (float, [pos*4+hh], CSR-ordered -> coalesced)
__global__ __launch_bounds__(256) void fused_agg_kernel(
    const __half* __restrict__ hp, const float* __restrict__ a_s, const float* __restrict__ a_d,
    const float* __restrict__ aecl, const int* __restrict__ srcs, const int* __restrict__ rowptr,
    const float* __restrict__ bias_l, const float* __restrict__ ln_g_l,
    const float* __restrict__ ln_b_l, float* __restrict__ h){
  __shared__ float wsm[4][CAP*4];
  __shared__ int   ssm[4][CAP];
  int wv = threadIdx.x >> 6;
  int n = blockIdx.x*4 + wv;
  int lane = threadIdx.x & 63;
  int p0 = rowptr[n], p1 = rowptr[n+1];
  int deg = p1 - p0 - 1;                       // real incoming edges
  int hh = lane & 3;                           // head this lane computes alphas for
  int esl = lane >> 2;                         // edge slot 0..15
  float adv = a_d[n*4 + hh];
  float asn = a_s[n*4 + hh];
  bool fits = (deg <= CAP);

  // phase 1: online softmax over real edges; cache alpha+src in LDS
  float m = -3.4e38f, ls = 0.f, ssum = 0.f;
  for (int base = 0; base < deg; base += 16){
    int idx = base + esl;
    if (idx < deg){
      int p = p0 + idx;
      float aev = aecl[(size_t)p*4 + hh];
      int sv = srcs[p];
      float al = a_s[sv*4 + hh] + adv + aev;
      al = (al > 0.f) ? al : 0.2f*al;          // leaky_relu 0.2
      ssum += aev;
      if (fits){
        wsm[wv][idx*4 + hh] = al;
        if (hh == 0) ssm[wv][idx] = sv;
      }
      if (al > m){ ls = ls*__expf(m - al) + 1.f; m = al; }
      else ls += __expf(al - m);
    }
  }
  // butterfly over the 16 lanes sharing head hh
  #pragma unroll
  for (int off = 4; off <= 32; off <<= 1){
    float mo = __shfl_xor(m, off);
    float lo = __shfl_xor(ls, off);
    float so = __shfl_xor(ssum, off);
    ssum += so;
    float mn = fmaxf(m, mo);
    ls = ls*__expf(m - mn) + lo*__expf(mo - mn);
    m = mn;
  }
  // self loop: a_e = mean of real-edge a_e (mean commutes with the linear map)
  float aself = ssum / (float)(deg > 0 ? deg : 1);
  float als = asn + adv + aself;
  als = (als > 0.f) ? als : 0.2f*als;
  float mx = fmaxf(m, als);
  float denom = ls*__expf(m - mx) + __expf(als - mx);
  float invd = 1.f/denom;

  // convert cached alphas to normalized weights (same lane->slot mapping; in-wave LDS order)
  if (fits){
    for (int base = 0; base < deg; base += 16){
      int idx = base + esl;
      if (idx < deg){
        float al = wsm[wv][idx*4 + hh];
        wsm[wv][idx*4 + hh] = __expf(al - mx)*invd;
      }
    }
  }

  int hsel = lane >> 4;                        // head of this lane's output columns
  float mxh   = __shfl(mx, hsel);
  float invdh = __shfl(invd, hsel);
  float alsh  = __shfl(als, hsel);

  // phase 2: weighted aggregation
  float acc0 = 0.f, acc1 = 0.f;
  if (fits){
    for (int j = 0; j < deg; j++){
      float w = wsm[wv][j*4 + hsel];
      int  sj = ssm[wv][j];
      __half2 hv = *((const __half2*)(hp + (size_t)sj*128) + lane);
      acc0 += w*__half2float(hv.x);
      acc1 += w*__half2float(hv.y);
    }
  } else {
    for (int base = 0; base < deg; base += 16){
      int idx = base + esl;
      float wgt = 0.f; int sv = 0;
      if (idx < deg){
        int p = p0 + idx;
        float aev = aecl[(size_t)p*4 + hh];
        sv = srcs[p];
        float al = a_s[sv*4 + hh] + adv + aev;
        al = (al > 0.f) ? al : 0.2f*al;
        wgt = __expf(al - mx)*invd;            // lane's own head == hh
      }
      int cnt_e = min(16, deg - base);
      for (int j = 0; j < cnt_e; j++){
        float w = __shfl(wgt, j*4 + hsel);
        int  sj = __shfl(sv,  j*4);
        __half2 hv = *((const __half2*)(hp + (size_t)sj*128) + lane);
        acc0 += w*__half2float(hv.x);
        acc1 += w*__half2float(hv.y);
      }
    }
  }
  {  // self contribution
    float w = __expf(alsh - mxh)*invdh;
    __half2 hv = *((const __half2*)(hp + (size_t)n*128) + lane);
    acc0 += w*__half2float(hv.x);
    acc1 += w*__half2float(hv.y);
  }
  // bias + residual + LayerNorm
  float2 res = *(const float2*)(h + (size_t)n*128 + lane*2);
  float2 bi  = *(const float2*)(bias_l + lane*2);
  float v0 = acc0 + bi.x + res.x;
  float v1 = acc1 + bi.y + res.y;
  float s = v0 + v1, sq = v0*v0 + v1*v1;
  #pragma unroll
  for (int off = 32; off >= 1; off >>= 1){ s += __shfl_xor(s, off); sq += __shfl_xor(sq, off); }
  float mu  = s * (1.0f/128.0f);
  float var = sq * (1.0f/128.0f) - mu*mu;
  float rs  = rsqrtf(fmaxf(var, 0.0f) + 1e-5f);
  float2 g  = *(const float2*)(ln_g_l + lane*2);
  float2 bb = *(const float2*)(ln_b_l + lane*2);
  float2 o;
  o.x = (v0 - mu)*rs*g.x + bb.x;
  o.y = (v1 - mu)*rs*g.y + bb.y;
  *(float2*)(h + (size_t)n*128 + lane*2) = o;
}

// ================= pooling partials (deterministic) =================
__global__ __launch_bounds__(128) void pool_part_kernel(const float* __restrict__ h,
                                                        float* __restrict__ psum, float* __restrict__ pmax){
  int b = blockIdx.x, j = threadIdx.x;
  int nb = b*(N_NODES/PB), ne = nb + (N_NODES/PB);
  float s = 0, m = -3.4e38f;
  for (int n = nb; n < ne; n++){ float v = h[(size_t)n*128 + j]; s += v; m = fmaxf(m, v); }
  psum[b*128 + j] = s; pmax[b*128 + j] = m;
}

// ================= pooled MLP + global head (f32 out) =================
__global__ __launch_bounds__(128) void global_kernel(
    const float* __restrict__ psum, const float* __restrict__ pmax,
    const float* __restrict__ u, const float* __restrict__ pool_w, const float* __restrict__ pool_b,
    const float* __restrict__ pool_ln_g, const float* __restrict__ pool_ln_b,
    const float* __restrict__ glob_w1, const float* __restrict__ glob_b1,
    const float* __restrict__ glob_w2, const float* __restrict__ glob_b2, float* __restrict__ out_glob){
  __shared__ float pooled[392];
  __shared__ float gv[8];
  __shared__ float t1[32];
  __shared__ float mv[2];
  int t = threadIdx.x;
  float s = 0, m = -3.4e38f;
  for (int b = 0; b < PB; b++){ s += psum[b*128 + t]; m = fmaxf(m, pmax[b*128 + t]); }
  pooled[t]       = s * (1.0f/(float)N_NODES);
  pooled[128 + t] = m;
  pooled[256 + t] = s;
  if (t < 8) pooled[384 + t] = u[t];
  __syncthreads();
  if (t < 8){
    float acc = pool_b[t];
    for (int f = 0; f < 392; f++) acc += pooled[f]*pool_w[f*8 + t];
    gv[t] = fmaxf(acc, 0.0f);
  }
  __syncthreads();
  if (t == 0){
    float mu = 0; for (int i = 0; i < 8; i++) mu += gv[i];
    mu *= 0.125f;
    float var = 0; for (int i = 0; i < 8; i++){ float d = gv[i]-mu; var += d*d; }
    var *= 0.125f;
    mv[0] = mu; mv[1] = rsqrtf(var + 1e-5f);
  }
  __syncthreads();
  float gnorm = (t < 8) ? (gv[t]-mv[0])*mv[1]*pool_ln_g[t] + pool_ln_b[t] : 0.0f;
  __syncthreads();
  if (t < 8) gv[t] = gnorm;
  __syncthreads();
  if (t < 32){
    float acc = glob_b1[t];
    for (int q = 0; q < 8; q++) acc += gv[q]*glob_w1[q*32 + t];
    t1[t] = fmaxf(acc, 0.0f);
  }
  __syncthreads();
  if (t < 4){
    float acc = glob_b2[t];
    for (int mm = 0; mm < 32; mm++) acc += t1[mm]*glob_w2[mm*4 + t];
    out_glob[t] = tanhf(acc);
  }
}

// ================= finalize: heads + strategies (f32 out) =================
__global__ void finalize_kernel(
    const float* __restrict__ z, const float* __restrict__ head_w2, const float* __restrict__ head_b2,
    const float* __restrict__ strat_w2, const float* __restrict__ strat_b2, float* __restrict__ out){
  int n = blockIdx.x*256 + threadIdx.x;
  if (n >= N_NODES) return;
  const float* zr = z + (size_t)n*160;
  float y[4];
  #pragma unroll
  for (int k = 0; k < 4; k++){
    float acc = head_b2[k];
    #pragma unroll
    for (int m = 0; m < 32; m++) acc += zr[k*32+m]*head_w2[k*32+m];
    y[k] = acc;
  }
  out[n]             = tanhf(y[0]);
  out[N_NODES + n]   = 1.0f/(1.0f + expf(-y[1]));
  out[2*N_NODES + n] = 1.0f/(1.0f + expf(-y[2]));
  out[3*N_NODES + n] = 1.0f/(1.0f + expf(-y[3]));
  float sv[5], mx = -3.4e38f;
  #pragma unroll
  for (int j = 0; j < 5; j++){
    float acc = strat_b2[j];
    #pragma unroll
    for (int m = 0; m < 32; m++) acc += zr[128+m]*strat_w2[m*5+j];
    sv[j] = acc; mx = fmaxf(mx, acc);
  }
  float se = 0;
  #pragma unroll
  for (int j = 0; j < 5; j++){ sv[j] = expf(sv[j]-mx); se += sv[j]; }
  float inv = 1.0f/se;
  #pragma unroll
  for (int j = 0; j < 5; j++) out[4*N_NODES + (size_t)n*5 + j] = sv[j]*inv;
}

// ======================================================================
extern "C" void kernel_launch(void* const* d_in, const int* in_sizes, int n_in,
                              void* d_out, int out_size, void* d_ws, size_t ws_size,
                              hipStream_t stream){
  float* out = (float*)d_out;

  static const int exp_sizes[30] = {
    750000, 1200000, 6000000, 8, 1920, 128, 49152, 384, 384, 3840, 384,
    384, 384, 384, 3136, 8, 8, 8, 16384, 128, 128, 4, 4096, 32, 160, 5,
    256, 32, 128, 4 };
  int host_code = 0;
  if (n_in != 30){
    int nn = n_in < 0 ? 0 : (n_in > 63 ? 63 : n_in);
    host_code = 4096 + 32*nn;
  } else {
    for (int i = 0; i < 30; i++)
      if (in_sizes[i] != exp_sizes[i]){ host_code = 1024 + 8*i; break; }
  }
  if (!host_code && out_size != 9*N_NODES + 4) host_code = 12288;
  if (host_code){
    sentinel_kernel<<<1, 64, 0, stream>>>(host_code, nullptr, nullptr, out);
    return;
  }

  const int* ei = (const int*)d_in[1];

  char* wsp = (char*)d_ws;
  size_t off = 0;
  auto alloc = [&](size_t bytes)->char*{ char* p = wsp + off; off += (bytes + 255) & ~(size_t)255; return p; };

  float*  h    = (float*)alloc((size_t)N_NODES*128*4);    // 25.6 MB
  __half* hp   = (__half*)alloc((size_t)N_NODES*128*2);   // 12.8 MB
  float*  a_s  = (float*)alloc((size_t)N_NODES*4*4);      // 0.8 MB
  float*  a_d  = (float*)alloc((size_t)N_NODES*4*4);      // 0.8 MB
  float*  aec  = (float*)alloc((size_t)3*TOT_E*16);       // 31.2 MB (float4 per pos per layer)
  // z[N][160] f32 = 32 MB aliases hp+a_s+a_d+aec (45.6 MB span) — all dead before heads GEMM
  float*  zbuf = (float*)hp;
  int*   srcs   = (int*)alloc((size_t)TOT_E*4);
  int*   pos_of = (int*)alloc((size_t)N_EDGES*4);
  int*   rowptr = (int*)alloc((size_t)(N_NODES+1)*4);
  int*   bsum   = (int*)alloc((size_t)NSB*4);

  const int SN = 27;
  static const int sn_sizes[SN] = {
    8, 1920, 128, 49152, 384, 384, 3840, 384, 384, 384, 384,
    3136, 8, 8, 8, 16384, 128, 128, 4, 4096, 32, 160, 5, 256, 32, 128, 4 };
  static const int sn_input[SN] = {
    3, 4, 5, 6, 7, 8, 9, 10, 11, 12, 13, 14, 15, 16, 17,
    18, 19, 20, 21, 22, 23, 24, 25, 26, 27, 28, 29 };
  float* sarr[SN];
  for (int i = 0; i < SN; i++) sarr[i] = (float*)alloc((size_t)sn_sizes[i]*4);
  float* u_c       = sarr[0];
  float* enc_w_c   = sarr[1];
  float* enc_b_c   = sarr[2];
  float* Wl        = sarr[3];
  float* att_src_c = sarr[4];
  float* att_dst_c = sarr[5];
  float* lin_e_c   = sarr[6];
  float* att_e_c   = sarr[7];
  float* bias_c    = sarr[8];
  float* ln_g_c    = sarr[9];
  float* ln_b_c    = sarr[10];
  float* pool_w_c  = sarr[11];
  float* pool_b_c  = sarr[12];
  float* pln_g_c   = sarr[13];
  float* pln_b_c   = sarr[14];
  float* head_w1_c = sarr[15];
  float* head_b1_c = sarr[16];
  float* head_w2_c = sarr[17];
  float* head_b2_c = sarr[18];
  float* strat_w1_c= sarr[19];
  float* strat_b1_c= sarr[20];
  float* strat_w2_c= sarr[21];
  float* strat_b2_c= sarr[22];
  float* glob_w1_c = sarr[23];
  float* glob_b1_c = sarr[24];
  float* glob_w2_c = sarr[25];
  float* glob_b2_c = sarr[26];

  float* W1cat  = (float*)alloc((size_t)128*160*4);
  float* b1cat  = (float*)alloc(160*4);
  float* Mmat   = (float*)alloc(3*40*4);
  int*   mode   = (int*)alloc(256);
  float* psum   = (float*)alloc((size_t)PB*128*4);
  float* pmax   = (float*)alloc((size_t)PB*128*4);
  size_t zero_begin = off;
  int*   devflags = (int*)alloc(256);
  int*   cnt      = (int*)alloc((size_t)N_NODES*4);
  int*   fill     = (int*)alloc((size_t)N_NODES*4);
  size_t zero_bytes = off - zero_begin;

  if (ws_size < off){
    sentinel_kernel<<<1, 64, 0, stream>>>(8192, nullptr, nullptr, out);
    return;
  }

  hipMemsetAsync(wsp + zero_begin, 0, zero_bytes, stream);

  detect_kernel<<<1, 256, 0, stream>>>(d_in[4], mode);

  CvtTab tab;
  for (int i = 0; i < SN; i++){ tab.s[i] = d_in[sn_input[i]]; tab.d[i] = sarr[i]; tab.n[i] = sn_sizes[i]; }
  cvt_small_kernel<<<dim3(SN, 192), 256, 0, stream>>>(tab, mode);

  pack_kernel<<<(128*160 + 255)/256, 256, 0, stream>>>(head_w1_c, strat_w1_c, head_b1_c, strat_b1_c, W1cat, b1cat);
  mmat_kernel<<<1, 128, 0, stream>>>(lin_e_c, att_e_c, Mmat);
  count_kernel<<<(N_EDGES + 255)/256, 256, 0, stream>>>(ei, cnt, devflags);
  scan1_kernel<<<NSB, SCB, 0, stream>>>(cnt, bsum);
  scan2_kernel<<<1, 64, 0, stream>>>(bsum, rowptr);
  scan3_kernel<<<NSB, SCB, 0, stream>>>(cnt, bsum, rowptr);
  scatter_kernel<<<(TOT_E + 255)/256, 256, 0, stream>>>(ei, rowptr, fill, srcs, pos_of);
  ae_kernel<<<(N_EDGES + 255)/256, 256, 0, stream>>>(d_in[2], mode, Mmat, pos_of, (float4*)aec);
  encoder_kernel<<<N_NODES, 128, 0, stream>>>(d_in[0], mode, enc_w_c, enc_b_c, h);

  const int gx = (N_NODES + 127)/128;   // 391
  for (int l = 0; l < NLAYER; l++){
    gemm_kernel<<<dim3(gx, 1), 256, 0, stream>>>(h, Wl + (size_t)l*128*128, nullptr, hp, N_NODES, 128, 0,
                                                 nullptr, att_src_c + l*128, att_dst_c + l*128, a_s, a_d);
    fused_agg_kernel<<<N_NODES/4, 256, 0, stream>>>(hp, a_s, a_d, aec + (size_t)l*TOT_E*4, srcs, rowptr,
                                                    bias_c + l*128, ln_g_c + l*128, ln_b_c + l*128, h);
  }

  pool_part_kernel<<<PB, 128, 0, stream>>>(h, psum, pmax);
  global_kernel<<<1, 128, 0, stream>>>(psum, pmax, u_c, pool_w_c, pool_b_c, pln_g_c, pln_b_c,
                                       glob_w1_c, glob_b1_c, glob_w2_c, glob_b2_c, out + 9*N_NODES);
  gemm_kernel<<<dim3(gx, 2), 256, 0, stream>>>(h, W1cat, zbuf, nullptr, N_NODES, 160, 1, b1cat,
                                               nullptr, nullptr, nullptr, nullptr);
  finalize_kernel<<<(N_NODES + 255)/256, 256, 0, stream>>>(zbuf, head_w2_c, head_b2_c, strat_w2_c, strat_b2_c, out);
  sentinel_kernel<<<1, 64, 0, stream>>>(0, devflags, mode, out);
}

// Round 8
// 530.991 us; speedup vs baseline: 2.4573x; 1.0448x over previous
//
#include <hip/hip_runtime.h>
#include <hip/hip_bf16.h>
#include <hip/hip_fp16.h>

#define N_NODES 50000
#define N_EDGES 600000
#define TOT_E   (N_EDGES + N_NODES)   // 650000 with self loops
#define NLAYER  3
#define PB      200                   // pool partial blocks
#define SCB     512                   // scan block
#define NSB     ((N_NODES + SCB - 1)/SCB)   // 98
#define CAP     96                    // max cached in-degree in fused_agg

typedef __hip_bfloat16 bf16;
typedef __attribute__((ext_vector_type(8))) short short8;
typedef __attribute__((ext_vector_type(4))) float floatx4;

__device__ __forceinline__ float b2f(bf16 v){ return __bfloat162float(v); }

// dual-mode load: m=1 -> f32, m=0 -> bf16
__device__ __forceinline__ float ldm(const void* p, long i, int m){
  return m ? ((const float*)p)[i] : b2f(((const bf16*)p)[i]);
}

// RNE float -> bf16 bits
__device__ __forceinline__ unsigned bfr(float f){
  unsigned u = __float_as_uint(f);
  return (u + 0x7fffu + ((u>>16)&1u)) >> 16;
}

// ================= input dtype detection =================
__global__ void detect_kernel(const void* probe, int* mode){
  __shared__ float red[256];
  int t = threadIdx.x;
  const bf16* p = (const bf16*)probe;
  float mx = 0.f;
  for (int i = t; i < 1920; i += 256){
    float v = fabsf(b2f(p[i]));
    if (!isfinite(v)) v = 1e30f;
    mx = fmaxf(mx, v);
  }
  red[t] = mx; __syncthreads();
  if (t == 0){
    float m = 0.f;
    for (int i = 0; i < 256; i++) m = fmaxf(m, red[i]);
    mode[0] = (m > 1000.0f) ? 1 : 0;
  }
}

// ================= sentinel (f32 output) =================
__global__ void sentinel_kernel(int host_code, const int* devflags, const int* mode, float* out){
  if (threadIdx.x == 0 && blockIdx.x == 0){
    int code = host_code;
    if (!code && devflags){
      if (devflags[1] > 900)      code = 16384;
      else if (devflags[0])       code = 20480;
    }
    if (code){
      if (mode) code += 512*mode[0];
      out[0] = (float)code;
    }
  }
}

// ================= small weight conversion (2-D grid) =================
struct CvtTab { const void* s[27]; float* d[27]; int n[27]; };
__global__ void cvt_small_kernel(CvtTab tab, const int* mode){
  int b = blockIdx.x;
  int i = blockIdx.y*256 + threadIdx.x;
  if (i < tab.n[b]) tab.d[b][i] = ldm(tab.s[b], i, mode[0]);
}

// ================= count + edge sanity =================
__global__ void count_kernel(const int* __restrict__ ei, int* __restrict__ cnt, int* devflags){
  int e = blockIdx.x*256 + threadIdx.x;
  if (e >= N_EDGES) return;
  int s = ei[e], d = ei[N_EDGES + e];
  if (((unsigned)s >= N_NODES) || ((unsigned)d >= N_NODES)) atomicOr(&devflags[0], 1);
  else atomicAdd(&cnt[d], 1);
  if (e < 1024 && ei[2*e + 1] == 0) atomicAdd(&devflags[1], 1);
}

// ================= hierarchical exclusive scan of (cnt[i]+1) =================
__global__ __launch_bounds__(SCB) void scan1_kernel(const int* __restrict__ cnt, int* __restrict__ bsum){
  __shared__ int ws[SCB/64];
  int i = blockIdx.x*SCB + threadIdx.x;
  int v = (i < N_NODES) ? cnt[i] + 1 : 0;
  int lane = threadIdx.x & 63, w = threadIdx.x >> 6;
  #pragma unroll
  for (int off = 1; off < 64; off <<= 1) v += __shfl_xor(v, off);
  if (lane == 0) ws[w] = v;
  __syncthreads();
  if (threadIdx.x == 0){
    int s = 0;
    #pragma unroll
    for (int k = 0; k < SCB/64; k++) s += ws[k];
    bsum[blockIdx.x] = s;
  }
}

__global__ void scan2_kernel(int* __restrict__ bsum, int* __restrict__ rowptr){
  if (threadIdx.x == 0 && blockIdx.x == 0){
    int run = 0;
    for (int b = 0; b < NSB; b++){ int t = bsum[b]; bsum[b] = run; run += t; }
    rowptr[N_NODES] = run;
  }
}

__global__ __launch_bounds__(SCB) void scan3_kernel(const int* __restrict__ cnt, const int* __restrict__ bsum,
                                                    int* __restrict__ rowptr){
  __shared__ int sm[SCB];
  int t = threadIdx.x;
  int i = blockIdx.x*SCB + t;
  int v = (i < N_NODES) ? cnt[i] + 1 : 0;
  sm[t] = v; __syncthreads();
  for (int off = 1; off < SCB; off <<= 1){
    int add = (t >= off) ? sm[t-off] : 0;
    __syncthreads();
    sm[t] += add;
    __syncthreads();
  }
  if (i < N_NODES) rowptr[i] = bsum[blockIdx.x] + sm[t] - v;   // exclusive
}

__global__ void scatter_kernel(const int* __restrict__ ei, const int* __restrict__ rowptr,
                               int* __restrict__ fill, int* __restrict__ srcs, int* __restrict__ pos_of){
  int e = blockIdx.x*256 + threadIdx.x;
  if (e >= TOT_E) return;
  if (e < N_EDGES){
    int s = ei[e], d = ei[N_EDGES + e];
    int pos = rowptr[d] + atomicAdd(&fill[d], 1);
    srcs[pos] = s; pos_of[e] = pos;
  } else {
    int i = e - N_EDGES;
    srcs[rowptr[i+1] - 1] = i;                 // last slot = self loop
  }
}

// ================= weight packing (fp32 W1cat + b1cat) =================
__global__ void pack_kernel(const float* __restrict__ head_w1, const float* __restrict__ strat_w1,
                            const float* __restrict__ head_b1, const float* __restrict__ strat_b1,
                            float* __restrict__ W1cat, float* __restrict__ b1cat){
  int t = blockIdx.x*256 + threadIdx.x;
  if (t < 128*160){
    int f = t / 160, c = t % 160;
    W1cat[t] = (c < 128) ? head_w1[(c>>5)*4096 + f*32 + (c&31)]
                         : strat_w1[f*32 + (c-128)];
  }
  if (t < 160) b1cat[t] = (t < 128) ? head_b1[t] : strat_b1[t-128];
}

// M[l][k][h] = sum_d We[l][k][h*32+d] * att_edge[l][h][d]   (edge-GEMM collapse)
__global__ void mmat_kernel(const float* __restrict__ We, const float* __restrict__ att_edge,
                            float* __restrict__ M){
  int t = threadIdx.x;
  if (t >= 120) return;
  int l = t / 40, r = t % 40, k = r / 4, hh = r % 4;
  float s = 0;
  #pragma unroll
  for (int d = 0; d < 32; d++)
    s += We[l*1280 + k*128 + hh*32 + d] * att_edge[l*128 + hh*32 + d];
  M[t] = s;
}

// Vsrc/Vdst[l][k][c]: c<4 = W·att_src head c, c>=4 = W·att_dst head c-4
__global__ void vsd_kernel(const float* __restrict__ Wl, const float* __restrict__ att_src,
                           const float* __restrict__ att_dst, float* __restrict__ vsd){
  int t = blockIdx.x*256 + threadIdx.x;
  if (t >= 3*128*8) return;
  int l = t >> 10, r = t & 1023;
  int k = r >> 3, c = r & 7;
  int sd = c >> 2, hh = c & 3;
  const float* w = Wl + l*16384 + k*128 + hh*32;
  const float* a = (sd ? att_dst : att_src) + l*128 + hh*32;
  float s = 0;
  #pragma unroll
  for (int d = 0; d < 32; d++) s += w[d]*a[d];
  vsd[t] = s;
}

// ================= pre-swizzle weights into MFMA B-fragment order, split hi/lo bf16 =================
// Bsw0[l][half][kt][n][kk]: n<128 = Wl cols; 128..135 = [Vsrc|Vdst]; 136..143 = 0.  (N=144, NT=9)
// Bsw1[half][kt][n][kk]: W1cat (N=160, NT=10)
__global__ void pack_bsw_kernel(const float* __restrict__ Wl, const float* __restrict__ vsd,
                                const float* __restrict__ W1cat,
                                ushort* __restrict__ Bsw0, ushort* __restrict__ Bsw1){
  int tid = blockIdx.x*256 + threadIdx.x;
  if (tid < 3*4*144*32){
    int l = tid / 18432, rr = tid % 18432;
    int kt = rr / 4608, r2 = rr % 4608;
    int n = r2 / 32, kk = r2 & 31;
    int k = kt*32 + kk;
    float f;
    if (n < 128)      f = Wl[l*16384 + k*128 + n];
    else if (n < 136) f = vsd[l*1024 + k*8 + (n - 128)];
    else              f = 0.f;
    unsigned hb = bfr(f);
    float fh = __uint_as_float(hb<<16);
    unsigned lb = bfr(f - fh);
    Bsw0[(size_t)(l*2+0)*18432 + kt*4608 + n*32 + kk] = (ushort)hb;
    Bsw0[(size_t)(l*2+1)*18432 + kt*4608 + n*32 + kk] = (ushort)lb;
  } else {
    int t2 = tid - 3*4*144*32;
    if (t2 >= 4*160*32) return;
    int kt = t2 / 5120, r2 = t2 % 5120;
    int n = r2 / 32, kk = r2 & 31;
    int k = kt*32 + kk;
    float f = W1cat[k*160 + n];
    unsigned hb = bfr(f);
    float fh = __uint_as_float(hb<<16);
    unsigned lb = bfr(f - fh);
    Bsw1[kt*5120 + n*32 + kk]          = (ushort)hb;
    Bsw1[4*5120 + kt*5120 + n*32 + kk] = (ushort)lb;
  }
}

// ================= encoder (dual-mode x) =================
__global__ __launch_bounds__(128) void encoder_kernel(const void* __restrict__ x_raw, const int* __restrict__ mode,
                                                      const float* __restrict__ enc_w, const float* __restrict__ enc_b,
                                                      float* __restrict__ h){
  __shared__ float xs[16];
  int n = blockIdx.x, j = threadIdx.x;
  if (j < 15) xs[j] = ldm(x_raw, (long)n*15 + j, mode[0]);
  __syncthreads();
  float acc = enc_b[j];
  #pragma unroll
  for (int k = 0; k < 15; k++) acc += xs[k] * enc_w[k*128 + j];
  h[(size_t)n*128 + j] = fmaxf(acc, 0.0f);
}

// ================= per-edge a_e, all layers, CSR order =================
__global__ void ae_kernel(const void* __restrict__ ea_raw, const int* __restrict__ mode,
                          const float* __restrict__ Mmat, const int* __restrict__ pos_of,
                          float4* __restrict__ aec){
  int e = blockIdx.x*256 + threadIdx.x;
  if (e >= N_EDGES) return;
  int m = mode[0];
  float v[10];
  #pragma unroll
  for (int k = 0; k < 10; k++) v[k] = ldm(ea_raw, (long)e*10 + k, m);
  int p = pos_of[e];
  #pragma unroll
  for (int l = 0; l < 3; l++){
    float r[4];
    #pragma unroll
    for (int hh = 0; hh < 4; hh++){
      float s = 0;
      #pragma unroll
      for (int k = 0; k < 10; k++) s += v[k]*Mmat[l*40 + k*4 + hh];
      r[hh] = s;
    }
    aec[(size_t)l*TOT_E + p] = make_float4(r[0], r[1], r[2], r[3]);
  }
}

// ================= MFMA GEMM (split-bf16, ~fp32 accurate), no LDS, no barriers =================
// One wave computes 16 rows x NT*16 cols, K=128 via 4 MFMA K-steps x 3 split terms.
// MODE 0 (NT=9): cols 0..127 -> hp fp16; col-tile 8 = [a_s heads 0-3 | a_d heads 0-3].
// MODE 1 (NT=10): bias + relu -> Cf (ld 160).
template<int NT, int MODE>
__global__ __launch_bounds__(256) void gemm_mfma(
    const float* __restrict__ A, const ushort* __restrict__ Bhi, const ushort* __restrict__ Blo,
    int M, const float* __restrict__ bias, __half* __restrict__ Ch, float* __restrict__ Cf,
    float* __restrict__ a_s, float* __restrict__ a_d){
  int wv = threadIdx.x >> 6, lane = threadIdx.x & 63;
  int nl = lane & 15, q = lane >> 4;
  int row0 = blockIdx.x*64 + wv*16;
  if (row0 >= M) return;
  floatx4 acc[NT];
  #pragma unroll
  for (int t = 0; t < NT; t++) acc[t] = (floatx4){0.f, 0.f, 0.f, 0.f};
  int ra = row0 + nl; if (ra > M-1) ra = M-1;
  const float* arow = A + (size_t)ra*128 + q*8;
  #pragma unroll
  for (int kt = 0; kt < 4; kt++){
    float4 a0 = *(const float4*)(arow + kt*32);
    float4 a1 = *(const float4*)(arow + kt*32 + 4);
    float af[8] = {a0.x,a0.y,a0.z,a0.w,a1.x,a1.y,a1.z,a1.w};
    short8 ahi, alo;
    #pragma unroll
    for (int j = 0; j < 8; j++){
      unsigned hb = bfr(af[j]);
      float fh = __uint_as_float(hb<<16);
      unsigned lb = bfr(af[j] - fh);
      ahi[j] = (short)hb; alo[j] = (short)lb;
    }
    const ushort* bh = Bhi + kt*(NT*16*32) + nl*32 + q*8;
    const ushort* bl = Blo + kt*(NT*16*32) + nl*32 + q*8;
    #pragma unroll
    for (int t = 0; t < NT; t++){
      short8 b0 = *(const short8*)(bh + t*512);
      short8 b1 = *(const short8*)(bl + t*512);
      acc[t] = __builtin_amdgcn_mfma_f32_16x16x32_bf16(ahi, b0, acc[t], 0, 0, 0);
      acc[t] = __builtin_amdgcn_mfma_f32_16x16x32_bf16(alo, b0, acc[t], 0, 0, 0);
      acc[t] = __builtin_amdgcn_mfma_f32_16x16x32_bf16(ahi, b1, acc[t], 0, 0, 0);
    }
  }
  #pragma unroll
  for (int r = 0; r < 4; r++){
    int row = row0 + q*4 + r;
    if (row >= M) continue;
    if (MODE == 0){
      #pragma unroll
      for (int t = 0; t < 8; t++)
        Ch[(size_t)row*128 + t*16 + nl] = __float2half(acc[t][r]);
      if (nl < 4)      a_s[row*4 + nl]       = acc[8][r];
      else if (nl < 8) a_d[row*4 + (nl - 4)] = acc[8][r];
    } else {
      #pragma unroll
      for (int t = 0; t < NT; t++){
        int col = t*16 + nl;
        Cf[(size_t)row*160 + col] = fmaxf(acc[t][r] + bias[col], 0.f);
      }
    }
  }
}

// ================= fused softmax + aggregate + residual + LN: one wave per node =================
__global__ __launch_bounds__(256) void fused_agg_kernel(
    const __half* __restrict__ hp, const float* __restrict__ a_s, const float* __restrict__ a_d,
    const float* __restrict__ aecl, const int* __restrict__ srcs, const int* __restrict__ rowptr,
    const float* __restrict__ bias_l, const float* __restrict__ ln_g_l,
    const float* __restrict__ ln_b_l, float* __restrict__ h){
  __shared__ float wsm[4][CAP*4];
  __shared__ int   ssm[4][CAP];
  int wv = threadIdx.x >> 6;
  int n = blockIdx.x*4 + wv;
  int lane = threadIdx.x & 63;
  int p0 = rowptr[n], p1 = rowptr[n+1];
  int deg = p1 - p0 - 1;
  int hh = lane & 3;
  int esl = lane >> 2;
  float adv = a_d[n*4 + hh];
  float asn = a_s[n*4 + hh];
  bool fits = (deg <= CAP);

  float m = -3.4e38f, ls = 0.f, ssum = 0.f;
  for (int base = 0; base < deg; base += 16){
    int idx = base + esl;
    if (idx < deg){
      int p = p0 + idx;
      float aev = aecl[(size_t)p*4 + hh];
      int sv = srcs[p];
      float al = a_s[sv*4 + hh] + adv + aev;
      al = (al > 0.f) ? al : 0.2f*al;
      ssum += aev;
      if (fits){
        wsm[wv][idx*4 + hh] = al;
        if (hh == 0) ssm[wv][idx] = sv;
      }
      if (al > m){ ls = ls*__expf(m - al) + 1.f; m = al; }
      else ls += __expf(al - m);
    }
  }
  #pragma unroll
  for (int off = 4; off <= 32; off <<= 1){
    float mo = __shfl_xor(m, off);
    float lo = __shfl_xor(ls, off);
    float so = __shfl_xor(ssum, off);
    ssum += so;
    float mn = fmaxf(m, mo);
    ls = ls*__expf(m - mn) + lo*__expf(mo - mn);
    m = mn;
  }
  float aself = ssum / (float)(deg > 0 ? deg : 1);
  float als = asn + adv + aself;
  als = (als > 0.f) ? als : 0.2f*als;
  float mx = fmaxf(m, als);
  float denom = ls*__expf(m - mx) + __expf(als - mx);
  float invd = 1.f/denom;

  if (fits){
    for (int base = 0; base < deg; base += 16){
      int idx = base + esl;
      if (idx < deg){
        float al = wsm[wv][idx*4 + hh];
        wsm[wv][idx*4 + hh] = __expf(al - mx)*invd;
      }
    }
  }

  int hsel = lane >> 4;
  float mxh   = __shfl(mx, hsel);
  float invdh = __shfl(invd, hsel);
  float alsh  = __shfl(als, hsel);

  float acc0 = 0.f, acc1 = 0.f;
  if (fits){
    for (int j = 0; j < deg; j++){
      float w = wsm[wv][j*4 + hsel];
      int  sj = ssm[wv][j];
      __half2 hv = *((const __half2*)(hp + (size_t)sj*128) + lane);
      acc0 += w*__half2float(hv.x);
      acc1 += w*__half2float(hv.y);
    }
  } else {
    for (int base = 0; base < deg; base += 16){
      int idx = base + esl;
      float wgt = 0.f; int sv = 0;
      if (idx < deg){
        int p = p0 + idx;
        float aev = aecl[(size_t)p*4 + hh];
        sv = srcs[p];
        float al = a_s[sv*4 + hh] + adv + aev;
        al = (al > 0.f) ? al : 0.2f*al;
        wgt = __expf(al - mx)*invd;
      }
      int cnt_e = min(16, deg - base);
      for (int j = 0; j < cnt_e; j++){
        float w = __shfl(wgt, j*4 + hsel);
        int  sj = __shfl(sv,  j*4);
        __half2 hv = *((const __half2*)(hp + (size_t)sj*128) + lane);
        acc0 += w*__half2float(hv.x);
        acc1 += w*__half2float(hv.y);
      }
    }
  }
  {
    float w = __expf(alsh - mxh)*invdh;
    __half2 hv = *((const __half2*)(hp + (size_t)n*128) + lane);
    acc0 += w*__half2float(hv.x);
    acc1 += w*__half2float(hv.y);
  }
  float2 res = *(const float2*)(h + (size_t)n*128 + lane*2);
  float2 bi  = *(const float2*)(bias_l + lane*2);
  float v0 = acc0 + bi.x + res.x;
  float v1 = acc1 + bi.y + res.y;
  float s = v0 + v1, sq = v0*v0 + v1*v1;
  #pragma unroll
  for (int off = 32; off >= 1; off >>= 1){ s += __shfl_xor(s, off); sq += __shfl_xor(sq, off); }
  float mu  = s * (1.0f/128.0f);
  float var = sq * (1.0f/128.0f) - mu*mu;
  float rs  = rsqrtf(fmaxf(var, 0.0f) + 1e-5f);
  float2 g  = *(const float2*)(ln_g_l + lane*2);
  float2 bb = *(const float2*)(ln_b_l + lane*2);
  float2 o;
  o.x = (v0 - mu)*rs*g.x + bb.x;
  o.y = (v1 - mu)*rs*g.y + bb.y;
  *(float2*)(h + (size_t)n*128 + lane*2) = o;
}

// ================= pooling partials (deterministic) =================
__global__ __launch_bounds__(128) void pool_part_kernel(const float* __restrict__ h,
                                                        float* __restrict__ psum, float* __restrict__ pmax){
  int b = blockIdx.x, j = threadIdx.x;
  int nb = b*(N_NODES/PB), ne = nb + (N_NODES/PB);
  float s = 0, m = -3.4e38f;
  for (int n = nb; n < ne; n++){ float v = h[(size_t)n*128 + j]; s += v; m = fmaxf(m, v); }
  psum[b*128 + j] = s; pmax[b*128 + j] = m;
}

// ================= pooled MLP + global head (f32 out) =================
__global__ __launch_bounds__(128) void global_kernel(
    const float* __restrict__ psum, const float* __restrict__ pmax,
    const float* __restrict__ u, const float* __restrict__ pool_w, const float* __restrict__ pool_b,
    const float* __restrict__ pool_ln_g, const float* __restrict__ pool_ln_b,
    const float* __restrict__ glob_w1, const float* __restrict__ glob_b1,
    const float* __restrict__ glob_w2, const float* __restrict__ glob_b2, float* __restrict__ out_glob){
  __shared__ float pooled[392];
  __shared__ float gv[8];
  __shared__ float t1[32];
  __shared__ float mv[2];
  int t = threadIdx.x;
  float s = 0, m = -3.4e38f;
  for (int b = 0; b < PB; b++){ s += psum[b*128 + t]; m = fmaxf(m, pmax[b*128 + t]); }
  pooled[t]       = s * (1.0f/(float)N_NODES);
  pooled[128 + t] = m;
  pooled[256 + t] = s;
  if (t < 8) pooled[384 + t] = u[t];
  __syncthreads();
  if (t < 8){
    float acc = pool_b[t];
    for (int f = 0; f < 392; f++) acc += pooled[f]*pool_w[f*8 + t];
    gv[t] = fmaxf(acc, 0.0f);
  }
  __syncthreads();
  if (t == 0){
    float mu = 0; for (int i = 0; i < 8; i++) mu += gv[i];
    mu *= 0.125f;
    float var = 0; for (int i = 0; i < 8; i++){ float d = gv[i]-mu; var += d*d; }
    var *= 0.125f;
    mv[0] = mu; mv[1] = rsqrtf(var + 1e-5f);
  }
  __syncthreads();
  float gnorm = (t < 8) ? (gv[t]-mv[0])*mv[1]*pool_ln_g[t] + pool_ln_b[t] : 0.0f;
  __syncthreads();
  if (t < 8) gv[t] = gnorm;
  __syncthreads();
  if (t < 32){
    float acc = glob_b1[t];
    for (int q = 0; q < 8; q++) acc += gv[q]*glob_w1[q*32 + t];
    t1[t] = fmaxf(acc, 0.0f);
  }
  __syncthreads();
  if (t < 4){
    float acc = glob_b2[t];
    for (int mm = 0; mm < 32; mm++) acc += t1[mm]*glob_w2[mm*4 + t];
    out_glob[t] = tanhf(acc);
  }
}

// ================= finalize: heads + strategies (f32 out) =================
__global__ void finalize_kernel(
    const float* __restrict__ z, const float* __restrict__ head_w2, const float* __restrict__ head_b2,
    const float* __restrict__ strat_w2, const float* __restrict__ strat_b2, float* __restrict__ out){
  int n = blockIdx.x*256 + threadIdx.x;
  if (n >= N_NODES) return;
  const float* zr = z + (size_t)n*160;
  float y[4];
  #pragma unroll
  for (int k = 0; k < 4; k++){
    float acc = head_b2[k];
    #pragma unroll
    for (int m = 0; m < 32; m++) acc += zr[k*32+m]*head_w2[k*32+m];
    y[k] = acc;
  }
  out[n]             = tanhf(y[0]);
  out[N_NODES + n]   = 1.0f/(1.0f + expf(-y[1]));
  out[2*N_NODES + n] = 1.0f/(1.0f + expf(-y[2]));
  out[3*N_NODES + n] = 1.0f/(1.0f + expf(-y[3]));
  float sv[5], mx = -3.4e38f;
  #pragma unroll
  for (int j = 0; j < 5; j++){
    float acc = strat_b2[j];
    #pragma unroll
    for (int m = 0; m < 32; m++) acc += zr[128+m]*strat_w2[m*5+j];
    sv[j] = acc; mx = fmaxf(mx, acc);
  }
  float se = 0;
  #pragma unroll
  for (int j = 0; j < 5; j++){ sv[j] = expf(sv[j]-mx); se += sv[j]; }
  float inv = 1.0f/se;
  #pragma unroll
  for (int j = 0; j < 5; j++) out[4*N_NODES + (size_t)n*5 + j] = sv[j]*inv;
}

// ======================================================================
extern "C" void kernel_launch(void* const* d_in, const int* in_sizes, int n_in,
                              void* d_out, int out_size, void* d_ws, size_t ws_size,
                              hipStream_t stream){
  float* out = (float*)d_out;

  static const int exp_sizes[30] = {
    750000, 1200000, 6000000, 8, 1920, 128, 49152, 384, 384, 3840, 384,
    384, 384, 384, 3136, 8, 8, 8, 16384, 128, 128, 4, 4096, 32, 160, 5,
    256, 32, 128, 4 };
  int host_code = 0;
  if (n_in != 30){
    int nn = n_in < 0 ? 0 : (n_in > 63 ? 63 : n_in);
    host_code = 4096 + 32*nn;
  } else {
    for (int i = 0; i < 30; i++)
      if (in_sizes[i] != exp_sizes[i]){ host_code = 1024 + 8*i; break; }
  }
  if (!host_code && out_size != 9*N_NODES + 4) host_code = 12288;
  if (host_code){
    sentinel_kernel<<<1, 64, 0, stream>>>(host_code, nullptr, nullptr, out);
    return;
  }

  const int* ei = (const int*)d_in[1];

  char* wsp = (char*)d_ws;
  size_t off = 0;
  auto alloc = [&](size_t bytes)->char*{ char* p = wsp + off; off += (bytes + 255) & ~(size_t)255; return p; };

  float*  h    = (float*)alloc((size_t)N_NODES*128*4);    // 25.6 MB
  __half* hp   = (__half*)alloc((size_t)N_NODES*128*2);   // 12.8 MB
  float*  a_s  = (float*)alloc((size_t)N_NODES*4*4);
  float*  a_d  = (float*)alloc((size_t)N_NODES*4*4);
  float*  aec  = (float*)alloc((size_t)3*TOT_E*16);       // 31.2 MB
  // z[N][160] f32 = 32 MB aliases hp+a_s+a_d+aec (45.6 MB span) — all dead before heads GEMM
  float*  zbuf = (float*)hp;
  int*   srcs   = (int*)alloc((size_t)TOT_E*4);
  int*   pos_of = (int*)alloc((size_t)N_EDGES*4);
  int*   rowptr = (int*)alloc((size_t)(N_NODES+1)*4);
  int*   bsum   = (int*)alloc((size_t)NSB*4);

  const int SN = 27;
  static const int sn_sizes[SN] = {
    8, 1920, 128, 49152, 384, 384, 3840, 384, 384, 384, 384,
    3136, 8, 8, 8, 16384, 128, 128, 4, 4096, 32, 160, 5, 256, 32, 128, 4 };
  static const int sn_input[SN] = {
    3, 4, 5, 6, 7, 8, 9, 10, 11, 12, 13, 14, 15, 16, 17,
    18, 19, 20, 21, 22, 23, 24, 25, 26, 27, 28, 29 };
  float* sarr[SN];
  for (int i = 0; i < SN; i++) sarr[i] = (float*)alloc((size_t)sn_sizes[i]*4);
  float* u_c       = sarr[0];
  float* enc_w_c   = sarr[1];
  float* enc_b_c   = sarr[2];
  float* Wl        = sarr[3];
  float* att_src_c = sarr[4];
  float* att_dst_c = sarr[5];
  float* lin_e_c   = sarr[6];
  float* att_e_c   = sarr[7];
  float* bias_c    = sarr[8];
  float* ln_g_c    = sarr[9];
  float* ln_b_c    = sarr[10];
  float* pool_w_c  = sarr[11];
  float* pool_b_c  = sarr[12];
  float* pln_g_c   = sarr[13];
  float* pln_b_c   = sarr[14];
  float* head_w1_c = sarr[15];
  float* head_b1_c = sarr[16];
  float* head_w2_c = sarr[17];
  float* head_b2_c = sarr[18];
  float* strat_w1_c= sarr[19];
  float* strat_b1_c= sarr[20];
  float* strat_w2_c= sarr[21];
  float* strat_b2_c= sarr[22];
  float* glob_w1_c = sarr[23];
  float* glob_b1_c = sarr[24];
  float* glob_w2_c = sarr[25];
  float* glob_b2_c = sarr[26];

  float*  W1cat = (float*)alloc((size_t)128*160*4);
  float*  b1cat = (float*)alloc(160*4);
  float*  Mmat  = (float*)alloc(3*40*4);
  float*  vsd   = (float*)alloc((size_t)3*128*8*4);
  ushort* Bsw0  = (ushort*)alloc((size_t)3*2*4*144*32*2);  // 216 KB
  ushort* Bsw1  = (ushort*)alloc((size_t)2*4*160*32*2);    // 80 KB
  int*    mode  = (int*)alloc(256);
  float*  psum  = (float*)alloc((size_t)PB*128*4);
  float*  pmax  = (float*)alloc((size_t)PB*128*4);
  size_t zero_begin = off;
  int*   devflags = (int*)alloc(256);
  int*   cnt      = (int*)alloc((size_t)N_NODES*4);
  int*   fill     = (int*)alloc((size_t)N_NODES*4);
  size_t zero_bytes = off - zero_begin;

  if (ws_size < off){
    sentinel_kernel<<<1, 64, 0, stream>>>(8192, nullptr, nullptr, out);
    return;
  }

  hipMemsetAsync(wsp + zero_begin, 0, zero_bytes, stream);

  detect_kernel<<<1, 256, 0, stream>>>(d_in[4], mode);

  CvtTab tab;
  for (int i = 0; i < SN; i++){ tab.s[i] = d_in[sn_input[i]]; tab.d[i] = sarr[i]; tab.n[i] = sn_sizes[i]; }
  cvt_small_kernel<<<dim3(SN, 192), 256, 0, stream>>>(tab, mode);

  pack_kernel<<<(128*160 + 255)/256, 256, 0, stream>>>(head_w1_c, strat_w1_c, head_b1_c, strat_b1_c, W1cat, b1cat);
  mmat_kernel<<<1, 128, 0, stream>>>(lin_e_c, att_e_c, Mmat);
  vsd_kernel<<<(3*128*8 + 255)/256, 256, 0, stream>>>(Wl, att_src_c, att_dst_c, vsd);
  pack_bsw_kernel<<<(3*4*144*32 + 4*160*32 + 255)/256, 256, 0, stream>>>(Wl, vsd, W1cat, Bsw0, Bsw1);

  count_kernel<<<(N_EDGES + 255)/256, 256, 0, stream>>>(ei, cnt, devflags);
  scan1_kernel<<<NSB, SCB, 0, stream>>>(cnt, bsum);
  scan2_kernel<<<1, 64, 0, stream>>>(bsum, rowptr);
  scan3_kernel<<<NSB, SCB, 0, stream>>>(cnt, bsum, rowptr);
  scatter_kernel<<<(TOT_E + 255)/256, 256, 0, stream>>>(ei, rowptr, fill, srcs, pos_of);
  ae_kernel<<<(N_EDGES + 255)/256, 256, 0, stream>>>(d_in[2], mode, Mmat, pos_of, (float4*)aec);
  encoder_kernel<<<N_NODES, 128, 0, stream>>>(d_in[0], mode, enc_w_c, enc_b_c, h);

  const int gb = (N_NODES + 63)/64;   // 782
  for (int l = 0; l < NLAYER; l++){
    const ushort* Bhi = Bsw0 + (size_t)l*2*18432;
    const ushort* Blo = Bhi + 18432;
    gemm_mfma<9,0><<<gb, 256, 0, stream>>>(h, Bhi, Blo, N_NODES, nullptr, hp, nullptr, a_s, a_d);
    fused_agg_kernel<<<N_NODES/4, 256, 0, stream>>>(hp, a_s, a_d, aec + (size_t)l*TOT_E*4, srcs, rowptr,
                                                    bias_c + l*128, ln_g_c + l*128, ln_b_c + l*128, h);
  }

  pool_part_kernel<<<PB, 128, 0, stream>>>(h, psum, pmax);
  global_kernel<<<1, 128, 0, stream>>>(psum, pmax, u_c, pool_w_c, pool_b_c, pln_g_c, pln_b_c,
                                       glob_w1_c, glob_b1_c, glob_w2_c, glob_b2_c, out + 9*N_NODES);
  gemm_mfma<10,1><<<gb, 256, 0, stream>>>(h, Bsw1, Bsw1 + 4*5120, N_NODES, b1cat, nullptr, zbuf,
                                          nullptr, nullptr);
  finalize_kernel<<<(N_NODES + 255)/256, 256, 0, stream>>>(zbuf, head_w2_c, head_b2_c, strat_w2_c, strat_b2_c, out);
  sentinel_kernel<<<1, 64, 0, stream>>>(0, devflags, mode, out);
}